// Round 10
// baseline (2188.224 us; speedup 1.0000x reference)
//
#include <hip/hip_runtime.h>
#include <hip/hip_bf16.h>
#include <hip/hip_fp16.h>
#include <math.h>

namespace {
constexpr int B_   = 2;
constexpr int C_   = 256;
constexpr int NH_  = 8;
constexpr int DH_  = 32;
constexpr int NP_  = 4;
constexpr int DFF_ = 1024;
constexpr int LQ_  = 21760;
constexpr int M_   = B_ * LQ_;     // 43520
}

typedef __bf16  bf16x8 __attribute__((ext_vector_type(8)));
typedef short   s16x8  __attribute__((ext_vector_type(8)));
typedef float   f32x4  __attribute__((ext_vector_type(4)));

#define AS1 __attribute__((address_space(1)))
#define AS3 __attribute__((address_space(3)))

static __device__ __forceinline__ unsigned short f2bf(float f) {
    return __builtin_bit_cast(unsigned short, __float2bfloat16(f));
}
static __device__ __forceinline__ float bf2f(unsigned short u) {
    return __bfloat162float(__builtin_bit_cast(__hip_bfloat16, u));
}

// ---------- weight transpose + cvt: in [L][K][N] f32 -> out rows [N][K] bf16 ----------
__global__ void k_wt(const float* __restrict__ in, __hip_bfloat16* __restrict__ out,
                     int K, int N, int outStride)
{
    __shared__ float tile[32][33];
    int n0 = blockIdx.x * 32, k0 = blockIdx.y * 32;
    const float* inl = in + (size_t)blockIdx.z * K * N;
    __hip_bfloat16* outl = out + (size_t)blockIdx.z * outStride;
    for (int i = threadIdx.y; i < 32; i += 8)
        tile[i][threadIdx.x] = inl[(size_t)(k0 + i) * N + n0 + threadIdx.x];
    __syncthreads();
    for (int i = threadIdx.y; i < 32; i += 8)
        outl[(size_t)(n0 + i) * K + k0 + threadIdx.x] = __float2bfloat16(tile[threadIdx.x][i]);
}

// ---------- coalesced assemble via LDS transpose ----------
__global__ __launch_bounds__(256) void k_assemble2(
    const float* __restrict__ s0, const float* __restrict__ s1,
    const float* __restrict__ s2, const float* __restrict__ s3,
    const float* __restrict__ p0, const float* __restrict__ p1,
    const float* __restrict__ p2, const float* __restrict__ p3,
    const float* __restrict__ lev, float* __restrict__ x,
    __hip_bfloat16* __restrict__ xbf, __hip_bfloat16* __restrict__ posbf,
    __hip_bfloat16* __restrict__ qbf)
{
    int bid = blockIdx.x;
    int lv, rem, HW, S0;
    const float *sp, *pp;
    if (bid < 8192)       { lv = 0; rem = bid;         HW = 16384; S0 = 0;     sp = s0; pp = p0; }
    else if (bid < 10240) { lv = 1; rem = bid - 8192;  HW = 4096;  S0 = 16384; sp = s1; pp = p1; }
    else if (bid < 10752) { lv = 2; rem = bid - 10240; HW = 1024;  S0 = 20480; sp = s2; pp = p2; }
    else                  { lv = 3; rem = bid - 10752; HW = 256;   S0 = 21504; sp = s3; pp = p3; }
    int sptiles = HW >> 5;
    int spt = rem % sptiles;
    int ct  = (rem / sptiles) & 7;
    int b   = rem / (sptiles * 8);
    int sp0 = spt * 32, c0 = ct * 32;

    __shared__ float ts[32][33], tp[32][33];
    int tx = threadIdx.x & 31, ty = threadIdx.x >> 5;
#pragma unroll
    for (int i = 0; i < 4; i++) {
        int c = c0 + ty + i * 8;
        size_t si = ((size_t)(b * C_ + c)) * HW + sp0 + tx;
        ts[ty + i * 8][tx] = sp[si];
        tp[ty + i * 8][tx] = pp[si];
    }
    __syncthreads();
#pragma unroll
    for (int i = 0; i < 4; i++) {
        int s = S0 + sp0 + ty + i * 8;
        int c = c0 + tx;
        float sv = ts[tx][ty + i * 8];
        float pv = tp[tx][ty + i * 8] + lev[lv * C_ + c];
        size_t idx = ((size_t)(b * LQ_ + s)) * C_ + c;
        x[idx]     = sv;
        xbf[idx]   = __float2bfloat16(sv);
        posbf[idx] = __float2bfloat16(pv);
        qbf[idx]   = __float2bfloat16(sv + pv);
    }
}

// ---------- merged q-GEMM: [off | attn] = q @ [Woff|Wattn] (N=384) ----------
__global__ __launch_bounds__(256) void k_gemm_qa(
    const __hip_bfloat16* __restrict__ A,     // [M,256]
    const __hip_bfloat16* __restrict__ Wq,    // [384,256]
    const float* __restrict__ boff, const float* __restrict__ battn,
    __half* __restrict__ offh, float* __restrict__ attb, int M)
{
    constexpr int K = 256;
    __shared__ char As[128 * 128];
    __shared__ char Bs[128 * 128];
    int t = threadIdx.x, w = t >> 6, lane = t & 63;
    int m0 = blockIdx.x * 128, n0 = blockIdx.y * 128;
    int wm = w >> 1, wn = w & 1;

    f32x4 acc[4][4] = {};
    int rowoff  = lane >> 3;
    int colswz  = ((lane & 7) ^ (lane >> 3)) << 3;

    for (int kt = 0; kt < K; kt += 64) {
#pragma unroll
        for (int j = 0; j < 4; j++) {
            int rowbase = w * 32 + j * 8;
            const __hip_bfloat16* srcA = A  + (size_t)(m0 + rowbase + rowoff) * K + kt + colswz;
            const __hip_bfloat16* srcB = Wq + (size_t)(n0 + rowbase + rowoff) * K + kt + colswz;
            __builtin_amdgcn_global_load_lds(
                (const AS1 void*)srcA, (AS3 void*)(As + rowbase * 128), 16, 0, 0);
            __builtin_amdgcn_global_load_lds(
                (const AS1 void*)srcB, (AS3 void*)(Bs + rowbase * 128), 16, 0, 0);
        }
        __syncthreads();
#pragma unroll
        for (int k0 = 0; k0 < 64; k0 += 32) {
            int kb = k0 * 2 + (lane >> 4) * 16;
            bf16x8 af[4], bfr[4];
#pragma unroll
            for (int mi = 0; mi < 4; mi++) {
                int r = wm * 64 + mi * 16 + (lane & 15);
                s16x8 raw = *(const s16x8*)(As + r * 128 + (kb ^ ((r & 7) << 4)));
                af[mi] = __builtin_bit_cast(bf16x8, raw);
            }
#pragma unroll
            for (int ni = 0; ni < 4; ni++) {
                int r = wn * 64 + ni * 16 + (lane & 15);
                s16x8 raw = *(const s16x8*)(Bs + r * 128 + (kb ^ ((r & 7) << 4)));
                bfr[ni] = __builtin_bit_cast(bf16x8, raw);
            }
#pragma unroll
            for (int mi = 0; mi < 4; mi++)
#pragma unroll
                for (int ni = 0; ni < 4; ni++)
                    acc[mi][ni] = __builtin_amdgcn_mfma_f32_16x16x32_bf16(
                        af[mi], bfr[ni], acc[mi][ni], 0, 0, 0);
        }
        __syncthreads();
    }

    if (blockIdx.y == 2) {
#pragma unroll
        for (int ni = 0; ni < 4; ni++) {
            int col = wn * 64 + ni * 16 + (lane & 15);
            float bb = battn[col];
#pragma unroll
            for (int mi = 0; mi < 4; mi++) {
                int row = m0 + wm * 64 + mi * 16 + ((lane >> 4) << 2);
#pragma unroll
                for (int r = 0; r < 4; r++)
                    attb[(size_t)(row + r) * 128 + col] = acc[mi][ni][r] + bb;
            }
        }
    } else {
#pragma unroll
        for (int ni = 0; ni < 4; ni++) {
            int col = n0 + wn * 64 + ni * 16 + (lane & 15);
            float bb = boff[col];
#pragma unroll
            for (int mi = 0; mi < 4; mi++) {
                int row = m0 + wm * 64 + mi * 16 + ((lane >> 4) << 2);
#pragma unroll
                for (int r = 0; r < 4; r++)
                    offh[(size_t)(row + r) * 256 + col] = __float2half(acc[mi][ni][r] + bb);
            }
        }
    }
}

// ---------- stage 64x256 bf16 tile into swizzled LDS (256 threads) ----------
static __device__ __forceinline__ void stage_x64(
    const __hip_bfloat16* __restrict__ src, int m0, char* xs, int w, int lane)
{
    int r  = lane >> 5;                 // 0/1
    int gl = lane & 31;                 // 16B granule in row
#pragma unroll
    for (int j = 0; j < 8; j++) {
        int row = (j * 4 + w) * 2 + r;
        int gsw = gl ^ (row & 7);
        const __hip_bfloat16* s = src + (size_t)(m0 + row) * 256 + gsw * 8;
        __builtin_amdgcn_global_load_lds(
            (const AS1 void*)s, (AS3 void*)(xs + (j * 4 + w) * 1024), 16, 0, 0);
    }
}

// ================== LN epilogue (BM=64, 4 waves x 64 cols) ==========
template<bool WRITE_Q>
static __device__ __forceinline__ void ln_epilogue64(
    f32x4 (&acc)[4][4], int m0, int w, int lane,
    const float* bias, float* xio, __hip_bfloat16* xbf,
    const float* g, const float* beta,
    const __hip_bfloat16* posb, __hip_bfloat16* qout,
    float (*sred1)[4], float (*sred2)[4])
{
    int cl = lane & 15;
    int rg = (lane >> 4) << 2;
    float bcol[4], gcol[4], btcol[4];
#pragma unroll
    for (int ni = 0; ni < 4; ni++) {
        int col = w * 64 + ni * 16 + cl;
        bcol[ni]  = bias[col];
        gcol[ni]  = g[col];
        btcol[ni] = beta[col];
    }

#pragma unroll
    for (int mi = 0; mi < 4; mi++)
#pragma unroll
    for (int r = 0; r < 4; r++) {
        int lr  = mi * 16 + rg + r;
        int row = m0 + lr;
        float s = 0.f;
#pragma unroll
        for (int ni = 0; ni < 4; ni++) {
            int col = w * 64 + ni * 16 + cl;
            float v = acc[mi][ni][r] + bcol[ni] + xio[(size_t)row * 256 + col];
            acc[mi][ni][r] = v;
            s += v;
        }
        s += __shfl_xor(s, 1); s += __shfl_xor(s, 2);
        s += __shfl_xor(s, 4); s += __shfl_xor(s, 8);
        if (cl == 0) sred1[lr][w] = s;
    }
    __syncthreads();

    float mu[4][4];
#pragma unroll
    for (int mi = 0; mi < 4; mi++)
#pragma unroll
    for (int r = 0; r < 4; r++) {
        int lr = mi * 16 + rg + r;
        mu[mi][r] = (sred1[lr][0] + sred1[lr][1] + sred1[lr][2] + sred1[lr][3]) * (1.f / 256.f);
        float s2 = 0.f;
#pragma unroll
        for (int ni = 0; ni < 4; ni++) {
            float d = acc[mi][ni][r] - mu[mi][r];
            s2 += d * d;
        }
        s2 += __shfl_xor(s2, 1); s2 += __shfl_xor(s2, 2);
        s2 += __shfl_xor(s2, 4); s2 += __shfl_xor(s2, 8);
        if (cl == 0) sred2[lr][w] = s2;
    }
    __syncthreads();

#pragma unroll
    for (int mi = 0; mi < 4; mi++)
#pragma unroll
    for (int r = 0; r < 4; r++) {
        int lr  = mi * 16 + rg + r;
        int row = m0 + lr;
        float var = (sred2[lr][0] + sred2[lr][1] + sred2[lr][2] + sred2[lr][3]) * (1.f / 256.f);
        float rstd = rsqrtf(var + 1e-5f);
#pragma unroll
        for (int ni = 0; ni < 4; ni++) {
            int col = w * 64 + ni * 16 + cl;
            size_t idx = (size_t)row * 256 + col;
            float o = (acc[mi][ni][r] - mu[mi][r]) * rstd * gcol[ni] + btcol[ni];
            xio[idx] = o;
            xbf[idx] = __float2bfloat16(o);
            if (WRITE_Q)
                qout[idx] = __float2bfloat16(o + bf2f(__builtin_bit_cast(unsigned short, posb[idx])));
        }
    }
}

// ---------- generic direct-B GEMM (K=256): out[M, by*256+...] bf16, optional relu ----------
// BM=64, 4 waves x 64 cols; stage A once; B fragments direct from global (L2-hot).
template<bool RELU>
__global__ __launch_bounds__(256) void k_gemm_direct(
    const __hip_bfloat16* __restrict__ A,     // [M,256]
    const __hip_bfloat16* __restrict__ Wt,    // [N,256]
    const float* __restrict__ bias,           // [N]
    __hip_bfloat16* __restrict__ out, int N)  // [M,N]
{
    __shared__ char xs[64 * 512];
    int t = threadIdx.x, w = t >> 6, lane = t & 63;
    int m0 = blockIdx.x * 64, n0 = blockIdx.y * 256;

    stage_x64(A, m0, xs, w, lane);
    asm volatile("s_waitcnt vmcnt(0)" ::: "memory");
    __builtin_amdgcn_s_barrier();

    f32x4 acc[4][4] = {};
#pragma unroll
    for (int k0 = 0; k0 < 256; k0 += 32) {
        int kb = k0 * 2 + (lane >> 4) * 16;
        bf16x8 af[4], bw[4];
#pragma unroll
        for (int mi = 0; mi < 4; mi++) {
            int r = mi * 16 + (lane & 15);
            s16x8 raw = *(const s16x8*)(xs + r * 512 + (kb ^ ((r & 7) << 4)));
            af[mi] = __builtin_bit_cast(bf16x8, raw);
        }
#pragma unroll
        for (int ni = 0; ni < 4; ni++) {
            int col = n0 + w * 64 + ni * 16 + (lane & 15);
            bw[ni] = *(const bf16x8*)(Wt + (size_t)col * 256 + k0 + (lane >> 4) * 8);
        }
#pragma unroll
        for (int mi = 0; mi < 4; mi++)
#pragma unroll
            for (int ni = 0; ni < 4; ni++)
                acc[mi][ni] = __builtin_amdgcn_mfma_f32_16x16x32_bf16(
                    af[mi], bw[ni], acc[mi][ni], 0, 0, 0);
    }

#pragma unroll
    for (int ni = 0; ni < 4; ni++) {
        int col = n0 + w * 64 + ni * 16 + (lane & 15);
        float bb = bias[col];
#pragma unroll
        for (int mi = 0; mi < 4; mi++) {
            int row = m0 + mi * 16 + ((lane >> 4) << 2);
#pragma unroll
            for (int r = 0; r < 4; r++) {
                float v = acc[mi][ni][r] + bb;
                if (RELU) v = fmaxf(v, 0.f);
                out[(size_t)(row + r) * N + col] = __float2bfloat16(v);
            }
        }
    }
}

// ---------- out-proj + LN: BM=64, K=256, B direct ----------
template<bool WRITE_Q>
__global__ __launch_bounds__(256) void k_out(
    const __hip_bfloat16* __restrict__ A,     // [M,256] sampled
    const __hip_bfloat16* __restrict__ Wt,    // [256,256]
    const float* __restrict__ bias,
    float* __restrict__ xio, __hip_bfloat16* __restrict__ xbf,
    const float* __restrict__ g, const float* __restrict__ beta,
    const __hip_bfloat16* __restrict__ posb, __hip_bfloat16* __restrict__ qout)
{
    __shared__ char xs[64 * 512];
    __shared__ float sred1[64][4];
    __shared__ float sred2[64][4];

    int t = threadIdx.x, w = t >> 6, lane = t & 63;
    int m0 = blockIdx.x * 64;

    stage_x64(A, m0, xs, w, lane);
    asm volatile("s_waitcnt vmcnt(0)" ::: "memory");
    __builtin_amdgcn_s_barrier();

    f32x4 acc[4][4] = {};
#pragma unroll
    for (int k0 = 0; k0 < 256; k0 += 32) {
        int kb = k0 * 2 + (lane >> 4) * 16;
        bf16x8 af[4], bw[4];
#pragma unroll
        for (int mi = 0; mi < 4; mi++) {
            int r = mi * 16 + (lane & 15);
            s16x8 raw = *(const s16x8*)(xs + r * 512 + (kb ^ ((r & 7) << 4)));
            af[mi] = __builtin_bit_cast(bf16x8, raw);
        }
#pragma unroll
        for (int ni = 0; ni < 4; ni++) {
            int col = w * 64 + ni * 16 + (lane & 15);
            bw[ni] = *(const bf16x8*)(Wt + (size_t)col * 256 + k0 + (lane >> 4) * 8);
        }
#pragma unroll
        for (int mi = 0; mi < 4; mi++)
#pragma unroll
            for (int ni = 0; ni < 4; ni++)
                acc[mi][ni] = __builtin_amdgcn_mfma_f32_16x16x32_bf16(
                    af[mi], bw[ni], acc[mi][ni], 0, 0, 0);
    }
    __syncthreads();

    ln_epilogue64<WRITE_Q>(acc, m0, w, lane, bias, xio, xbf, g, beta, posb, qout,
                           sred1, sred2);
}

// ---------- FF2 + residual + LN: BM=128, 512 thr, A-only dbuf, B direct ----------
template<bool WRITE_Q>
__global__ __launch_bounds__(512) void k_ff2ln(
    const __hip_bfloat16* __restrict__ A,    // [M,1024] ffh
    const __hip_bfloat16* __restrict__ Wt,   // [256,1024]
    const float* __restrict__ bias,
    float* __restrict__ xio, __hip_bfloat16* __restrict__ xbf,
    const float* __restrict__ g, const float* __restrict__ beta,
    const __hip_bfloat16* __restrict__ posb, __hip_bfloat16* __restrict__ qout,
    int M, int K)
{
    __shared__ char As[2][128 * 128];
    __shared__ float sred1[128][4];
    __shared__ float sred2[128][4];

    int t = threadIdx.x, w = t >> 6, lane = t & 63;
    int m0 = blockIdx.x * 128;
    int wm = w >> 2, wn = w & 3;

    f32x4 acc[4][4] = {};

    int rowoff  = lane >> 3;
    int colswz  = ((lane & 7) ^ rowoff) << 3;

    auto STAGE_A = [&](char* Ab, int kt) {
#pragma unroll
        for (int j = 0; j < 2; j++) {
            int rowbase = w * 16 + j * 8;
            const __hip_bfloat16* srcA = A + (size_t)(m0 + rowbase + rowoff) * K + kt + colswz;
            __builtin_amdgcn_global_load_lds(
                (const AS1 void*)srcA, (AS3 void*)(Ab + rowbase * 128), 16, 0, 0);
        }
    };

    STAGE_A(As[0], 0);
    asm volatile("s_waitcnt vmcnt(0)" ::: "memory");
    __builtin_amdgcn_s_barrier();

    const int nt = K >> 6;
    int cur = 0;
    for (int tt = 0; tt < nt; ++tt) {
        if (tt + 1 < nt) STAGE_A(As[cur ^ 1], (tt + 1) << 6);
        const char* Ab = As[cur];
        int ktb = tt << 6;
#pragma unroll
        for (int k0 = 0; k0 < 64; k0 += 32) {
            int kb = k0 * 2 + (lane >> 4) * 16;
            bf16x8 af[4], bw[4];
#pragma unroll
            for (int mi = 0; mi < 4; mi++) {
                int r = wm * 64 + mi * 16 + (lane & 15);
                s16x8 raw = *(const s16x8*)(Ab + r * 128 + (kb ^ ((r & 7) << 4)));
                af[mi] = __builtin_bit_cast(bf16x8, raw);
            }
#pragma unroll
            for (int ni = 0; ni < 4; ni++) {
                int col = wn * 64 + ni * 16 + (lane & 15);
                bw[ni] = *(const bf16x8*)(Wt + (size_t)col * K + ktb + k0 + (lane >> 4) * 8);
            }
#pragma unroll
            for (int mi = 0; mi < 4; mi++)
#pragma unroll
                for (int ni = 0; ni < 4; ni++)
                    acc[mi][ni] = __builtin_amdgcn_mfma_f32_16x16x32_bf16(
                        af[mi], bw[ni], acc[mi][ni], 0, 0, 0);
        }
        asm volatile("s_waitcnt vmcnt(0)" ::: "memory");
        __builtin_amdgcn_s_barrier();
        cur ^= 1;
    }

    // ---- fused bias + residual + LN epilogue (128-row) ----
    int cl = lane & 15;
    int rg = (lane >> 4) << 2;
    float bcol[4], gcol[4], btcol[4];
#pragma unroll
    for (int ni = 0; ni < 4; ni++) {
        int col = wn * 64 + ni * 16 + cl;
        bcol[ni]  = bias[col];
        gcol[ni]  = g[col];
        btcol[ni] = beta[col];
    }

#pragma unroll
    for (int mi = 0; mi < 4; mi++)
#pragma unroll
    for (int r = 0; r < 4; r++) {
        int lr  = wm * 64 + mi * 16 + rg + r;
        int row = m0 + lr;
        float s = 0.f;
#pragma unroll
        for (int ni = 0; ni < 4; ni++) {
            int col = wn * 64 + ni * 16 + cl;
            float v = acc[mi][ni][r] + bcol[ni] + xio[(size_t)row * 256 + col];
            acc[mi][ni][r] = v;
            s += v;
        }
        s += __shfl_xor(s, 1); s += __shfl_xor(s, 2);
        s += __shfl_xor(s, 4); s += __shfl_xor(s, 8);
        if (cl == 0) sred1[lr][wn] = s;
    }
    __syncthreads();

    float mu[4][4];
#pragma unroll
    for (int mi = 0; mi < 4; mi++)
#pragma unroll
    for (int r = 0; r < 4; r++) {
        int lr = wm * 64 + mi * 16 + rg + r;
        mu[mi][r] = (sred1[lr][0] + sred1[lr][1] + sred1[lr][2] + sred1[lr][3]) * (1.f / 256.f);
        float s2 = 0.f;
#pragma unroll
        for (int ni = 0; ni < 4; ni++) {
            float d = acc[mi][ni][r] - mu[mi][r];
            s2 += d * d;
        }
        s2 += __shfl_xor(s2, 1); s2 += __shfl_xor(s2, 2);
        s2 += __shfl_xor(s2, 4); s2 += __shfl_xor(s2, 8);
        if (cl == 0) sred2[lr][wn] = s2;
    }
    __syncthreads();

#pragma unroll
    for (int mi = 0; mi < 4; mi++)
#pragma unroll
    for (int r = 0; r < 4; r++) {
        int lr  = wm * 64 + mi * 16 + rg + r;
        int row = m0 + lr;
        float var = (sred2[lr][0] + sred2[lr][1] + sred2[lr][2] + sred2[lr][3]) * (1.f / 256.f);
        float rstd = rsqrtf(var + 1e-5f);
#pragma unroll
        for (int ni = 0; ni < 4; ni++) {
            int col = wn * 64 + ni * 16 + cl;
            size_t idx = (size_t)row * 256 + col;
            float o = (acc[mi][ni][r] - mu[mi][r]) * rstd * gcol[ni] + btcol[ni];
            xio[idx] = o;
            xbf[idx] = __float2bfloat16(o);
            if (WRITE_Q)
                qout[idx] = __float2bfloat16(o + bf2f(__builtin_bit_cast(unsigned short, posb[idx])));
        }
    }
}

// ---------- deformable sampling v4 ----------
__global__ __launch_bounds__(256) void k_sample4(const __hip_bfloat16* __restrict__ val,
                                                 const __half* __restrict__ offh,
                                                 const float* __restrict__ logits,
                                                 __hip_bfloat16* __restrict__ out)
{
    __shared__ int2 sIW[4 * 64 * 17];

    int t  = threadIdx.x;
    int qb = blockIdx.x;

#pragma unroll
    for (int it = 0; it < 4; it++) {
        int item = t + it * 256;
        int qi = item >> 7;
        int pt = item & 127;
        int bs = qb * 8 + qi;
        int b  = bs / LQ_;
        int s  = bs % LQ_;
        int h  = pt >> 4, lv = (pt >> 2) & 3;

        float lg = logits[(size_t)bs * 128 + pt];
        float mx = lg;
#pragma unroll
        for (int m = 1; m < 16; m <<= 1) mx = fmaxf(mx, __shfl_xor(mx, m));
        float ex = __expf(lg - mx);
        float sm = ex;
#pragma unroll
        for (int m = 1; m < 16; m <<= 1) sm += __shfl_xor(sm, m);
        float aw = ex / sm;

        int p0, Wq;
        if (s < 16384)      { p0 = s;         Wq = 128; }
        else if (s < 20480) { p0 = s - 16384; Wq = 64;  }
        else if (s < 21504) { p0 = s - 20480; Wq = 32;  }
        else                { p0 = s - 21504; Wq = 16;  }
        float invWq = 1.f / (float)Wq;
        float refx = ((p0 % Wq) + 0.5f) * invWq;
        float refy = ((p0 / Wq) + 0.5f) * invWq;

        int W  = 128 >> lv;
        int S0 = (65536 - (65536 >> (2 * lv))) / 3;
        float fW = (float)W;

        __half2 o2 = ((const __half2*)(offh + (size_t)bs * 256))[pt];
        float ox = __low2float(o2), oy = __high2float(o2);
        float xx = refx * fW + ox - 0.5f;
        float yy = refy * fW + oy - 0.5f;
        float x0f = floorf(xx), y0f = floorf(yy);
        float wx = xx - x0f, wy = yy - y0f;
        int x0 = (int)x0f, y0 = (int)y0f;
        int x1 = x0 + 1, y1 = y0 + 1;
        bool vx0 = (x0 >= 0) & (x0 < W), vx1 = (x1 >= 0) & (x1 < W);
        bool vy0 = (y0 >= 0) & (y0 < W), vy1 = (y1 >= 0) & (y1 < W);
        int cx0 = min(max(x0, 0), W - 1), cx1 = min(max(x1, 0), W - 1);
        int cy0 = min(max(y0, 0), W - 1), cy1 = min(max(y1, 0), W - 1);

        int rowbase = (b * LQ_ + S0) * C_ + h * DH_;
        int g  = item >> 4;
        int pj = pt & 15;
        int i00 = (rowbase + (cy0 * W + cx0) * C_) * 2;
        int i10 = (rowbase + (cy0 * W + cx1) * C_) * 2;
        int i01 = (rowbase + (cy1 * W + cx0) * C_) * 2;
        int i11 = (rowbase + (cy1 * W + cx1) * C_) * 2;
        float w00 = aw * (1.f - wx) * (1.f - wy) * ((vx0 & vy0) ? 1.f : 0.f);
        float w10 = aw * wx * (1.f - wy) * ((vx1 & vy0) ? 1.f : 0.f);
        float w01 = aw * (1.f - wx) * wy * ((vx0 & vy1) ? 1.f : 0.f);
        float w11 = aw * wx * wy * ((vx1 & vy1) ? 1.f : 0.f);
        sIW[(0 * 64 + g) * 17 + pj] = make_int2(i00, __float_as_int(w00));
        sIW[(1 * 64 + g) * 17 + pj] = make_int2(i10, __float_as_int(w10));
        sIW[(2 * 64 + g) * 17 + pj] = make_int2(i01, __float_as_int(w01));
        sIW[(3 * 64 + g) * 17 + pj] = make_int2(i11, __float_as_int(w11));
    }
    __syncthreads();

    {
        int g  = t >> 2;
        int dq = t & 3;
        int bs = qb * 8 + (g >> 3);
        int h  = g & 7;
        int dbyte = dq * 16;

        const char* vbase = (const char*)val;
        float a0 = 0.f, a1 = 0.f, a2 = 0.f, a3 = 0.f;
        float a4 = 0.f, a5 = 0.f, a6 = 0.f, a7 = 0.f;
#pragma unroll
        for (int j = 0; j < 16; j++) {
#pragma unroll
            for (int k = 0; k < 4; k++) {
                int2 iw = sIW[(k * 64 + g) * 17 + j];
                float w = __int_as_float(iw.y);
                uint4 u = *(const uint4*)(vbase + iw.x + dbyte);
                a0 = fmaf(w, __builtin_bit_cast(float, u.x << 16), a0);
                a1 = fmaf(w, __builtin_bit_cast(float, u.x & 0xffff0000u), a1);
                a2 = fmaf(w, __builtin_bit_cast(float, u.y << 16), a2);
                a3 = fmaf(w, __builtin_bit_cast(float, u.y & 0xffff0000u), a3);
                a4 = fmaf(w, __builtin_bit_cast(float, u.z << 16), a4);
                a5 = fmaf(w, __builtin_bit_cast(float, u.z & 0xffff0000u), a5);
                a6 = fmaf(w, __builtin_bit_cast(float, u.w << 16), a6);
                a7 = fmaf(w, __builtin_bit_cast(float, u.w & 0xffff0000u), a7);
            }
        }
        uint4 o;
        o.x = (unsigned)f2bf(a0) | ((unsigned)f2bf(a1) << 16);
        o.y = (unsigned)f2bf(a2) | ((unsigned)f2bf(a3) << 16);
        o.z = (unsigned)f2bf(a4) | ((unsigned)f2bf(a5) << 16);
        o.w = (unsigned)f2bf(a6) | ((unsigned)f2bf(a7) << 16);
        *(uint4*)((char*)out + (size_t)bs * 512 + h * 64 + dbyte) = o;
    }
}

// ---------- driver ----------
extern "C" void kernel_launch(void* const* d_in, const int* in_sizes, int n_in,
                              void* d_out, int out_size, void* d_ws, size_t ws_size,
                              hipStream_t stream)
{
    const float* src_[4] = {(const float*)d_in[0], (const float*)d_in[2],
                            (const float*)d_in[4], (const float*)d_in[6]};
    const float* pos_[4] = {(const float*)d_in[1], (const float*)d_in[3],
                            (const float*)d_in[5], (const float*)d_in[7]};
    const float* lev   = (const float*)d_in[8];
    const float* Woff  = (const float*)d_in[9];
    const float* boff  = (const float*)d_in[10];
    const float* Wattn = (const float*)d_in[11];
    const float* battn = (const float*)d_in[12];
    const float* Wval  = (const float*)d_in[13];
    const float* bval  = (const float*)d_in[14];
    const float* Wout  = (const float*)d_in[15];
    const float* bout  = (const float*)d_in[16];
    const float* g1    = (const float*)d_in[17];
    const float* b1    = (const float*)d_in[18];
    const float* Wff1  = (const float*)d_in[19];
    const float* bff1  = (const float*)d_in[20];
    const float* Wff2  = (const float*)d_in[21];
    const float* bff2  = (const float*)d_in[22];
    const float* g2    = (const float*)d_in[23];
    const float* b2    = (const float*)d_in[24];

    float* x = (float*)d_out;                       // persistent hidden state (fp32)
    size_t MC = (size_t)M_ * C_;                    // 11,141,120

    // layout (each mid segment = M*512 bytes):
    // pos | q | x_bf | offh(f16 M*256) | attb(f32 M*128) | val_bf | pad | weights
    // ffh [M,1024] bf16 aliases offh..pad exactly (4 x M*512 B).
    __hip_bfloat16* pos_bf = (__hip_bfloat16*)d_ws;
    __hip_bfloat16* q_bf   = pos_bf + MC;
    __hip_bfloat16* x_bf   = q_bf + MC;
    __half* offh           = (__half*)(x_bf + MC);            // M*256 f16
    float*  attb           = (float*)(offh + MC);             // M*128 f32
    __hip_bfloat16* val_bf = (__hip_bfloat16*)(attb + (size_t)M_ * 128);
    __hip_bfloat16* pad_bf = val_bf + MC;                     // ffh tail
    __hip_bfloat16* ffh_bf = (__hip_bfloat16*)offh;           // [M,1024] alias
    __hip_bfloat16* wbf    = pad_bf + MC;

    __hip_bfloat16* wq    = wbf;                        // 6*384*256
    __hip_bfloat16* wvalt = wq    + 6 * 98304;
    __hip_bfloat16* woutt = wvalt + 6 * 65536;
    __hip_bfloat16* wff1t = woutt + 6 * 65536;
    __hip_bfloat16* wff2t = wff1t + 6 * 262144;

    dim3 blk(256);
    dim3 tblk(32, 8);

    k_wt<<<dim3(8, 8, 6),  tblk, 0, stream>>>(Woff,  wq,               256, 256,  98304);
    k_wt<<<dim3(4, 8, 6),  tblk, 0, stream>>>(Wattn, wq + 256 * 256,   256, 128,  98304);
    k_wt<<<dim3(8, 8, 6),  tblk, 0, stream>>>(Wval,  wvalt,            256, 256,  65536);
    k_wt<<<dim3(8, 8, 6),  tblk, 0, stream>>>(Wout,  woutt,            256, 256,  65536);
    k_wt<<<dim3(32, 8, 6), tblk, 0, stream>>>(Wff1,  wff1t,            256, 1024, 262144);
    k_wt<<<dim3(8, 32, 6), tblk, 0, stream>>>(Wff2,  wff2t,            1024, 256, 262144);

    k_assemble2<<<10880, blk, 0, stream>>>(
        src_[0], src_[1], src_[2], src_[3],
        pos_[0], pos_[1], pos_[2], pos_[3], lev, x, x_bf, pos_bf, q_bf);

    for (int l = 0; l < 6; l++) {
        // off (f16) + attn logits (f32) in one GEMM (N=384)
        k_gemm_qa<<<dim3(M_ / 128, 3), blk, 0, stream>>>(
            q_bf, wq + (size_t)l * 98304, boff + l * 256, battn + l * 128,
            offh, attb, M_);

        // val = x @ Wval + bval  [M,256] bf16  (direct-B)
        k_gemm_direct<false><<<dim3(M_ / 64, 1), blk, 0, stream>>>(
            x_bf, wvalt + (size_t)l * 65536, bval + l * 256, val_bf, 256);

        // deformable sampling (softmax fused) -> q_bf
        k_sample4<<<M_ / 8, blk, 0, stream>>>(val_bf, offh, attb, q_bf);

        // out-proj + bias + residual + LN -> x, x_bf  (BM=64, direct-B)
        k_out<false><<<M_ / 64, blk, 0, stream>>>(
            q_bf, woutt + (size_t)l * 65536, bout + l * 256,
            x, x_bf, g1 + l * 256, b1 + l * 256, nullptr, nullptr);

        // FF1: ffh = relu(x@W1+b1)  (direct-B; ffh aliases offh/attb/val/pad)
        k_gemm_direct<true><<<dim3(M_ / 64, 4), blk, 0, stream>>>(
            x_bf, wff1t + (size_t)l * 262144, bff1 + l * DFF_, ffh_bf, DFF_);

        // FF2 + residual + LN (+ q for next layer)  (A-dbuf, direct-B)
        if (l < 5)
            k_ff2ln<true><<<M_ / 128, 512, 0, stream>>>(
                ffh_bf, wff2t + (size_t)l * 262144, bff2 + l * C_,
                x, x_bf, g2 + l * 256, b2 + l * 256, pos_bf, q_bf, M_, DFF_);
        else
            k_ff2ln<false><<<M_ / 128, 512, 0, stream>>>(
                ffh_bf, wff2t + (size_t)l * 262144, bff2 + l * C_,
                x, x_bf, g2 + l * 256, b2 + l * 256, nullptr, nullptr, M_, DFF_);
    }
}

// Round 11
// 1881.452 us; speedup vs baseline: 1.1631x; 1.1631x over previous
//
#include <hip/hip_runtime.h>
#include <hip/hip_bf16.h>
#include <hip/hip_fp16.h>
#include <math.h>

namespace {
constexpr int B_   = 2;
constexpr int C_   = 256;
constexpr int NH_  = 8;
constexpr int DH_  = 32;
constexpr int NP_  = 4;
constexpr int DFF_ = 1024;
constexpr int LQ_  = 21760;
constexpr int M_   = B_ * LQ_;     // 43520
}

typedef __bf16  bf16x8 __attribute__((ext_vector_type(8)));
typedef short   s16x8  __attribute__((ext_vector_type(8)));
typedef float   f32x4  __attribute__((ext_vector_type(4)));

#define AS1 __attribute__((address_space(1)))
#define AS3 __attribute__((address_space(3)))

static __device__ __forceinline__ unsigned short f2bf(float f) {
    return __builtin_bit_cast(unsigned short, __float2bfloat16(f));
}
static __device__ __forceinline__ float bf2f(unsigned short u) {
    return __bfloat162float(__builtin_bit_cast(__hip_bfloat16, u));
}

// ---------- weight transpose + cvt: in [L][K][N] f32 -> out rows [N][K] bf16 ----------
__global__ void k_wt(const float* __restrict__ in, __hip_bfloat16* __restrict__ out,
                     int K, int N, int outStride)
{
    __shared__ float tile[32][33];
    int n0 = blockIdx.x * 32, k0 = blockIdx.y * 32;
    const float* inl = in + (size_t)blockIdx.z * K * N;
    __hip_bfloat16* outl = out + (size_t)blockIdx.z * outStride;
    for (int i = threadIdx.y; i < 32; i += 8)
        tile[i][threadIdx.x] = inl[(size_t)(k0 + i) * N + n0 + threadIdx.x];
    __syncthreads();
    for (int i = threadIdx.y; i < 32; i += 8)
        outl[(size_t)(n0 + i) * K + k0 + threadIdx.x] = __float2bfloat16(tile[threadIdx.x][i]);
}

// ---------- coalesced assemble via LDS transpose ----------
__global__ __launch_bounds__(256) void k_assemble2(
    const float* __restrict__ s0, const float* __restrict__ s1,
    const float* __restrict__ s2, const float* __restrict__ s3,
    const float* __restrict__ p0, const float* __restrict__ p1,
    const float* __restrict__ p2, const float* __restrict__ p3,
    const float* __restrict__ lev, float* __restrict__ x,
    __hip_bfloat16* __restrict__ xbf, __hip_bfloat16* __restrict__ posbf,
    __hip_bfloat16* __restrict__ qbf)
{
    int bid = blockIdx.x;
    int lv, rem, HW, S0;
    const float *sp, *pp;
    if (bid < 8192)       { lv = 0; rem = bid;         HW = 16384; S0 = 0;     sp = s0; pp = p0; }
    else if (bid < 10240) { lv = 1; rem = bid - 8192;  HW = 4096;  S0 = 16384; sp = s1; pp = p1; }
    else if (bid < 10752) { lv = 2; rem = bid - 10240; HW = 1024;  S0 = 20480; sp = s2; pp = p2; }
    else                  { lv = 3; rem = bid - 10752; HW = 256;   S0 = 21504; sp = s3; pp = p3; }
    int sptiles = HW >> 5;
    int spt = rem % sptiles;
    int ct  = (rem / sptiles) & 7;
    int b   = rem / (sptiles * 8);
    int sp0 = spt * 32, c0 = ct * 32;

    __shared__ float ts[32][33], tp[32][33];
    int tx = threadIdx.x & 31, ty = threadIdx.x >> 5;
#pragma unroll
    for (int i = 0; i < 4; i++) {
        int c = c0 + ty + i * 8;
        size_t si = ((size_t)(b * C_ + c)) * HW + sp0 + tx;
        ts[ty + i * 8][tx] = sp[si];
        tp[ty + i * 8][tx] = pp[si];
    }
    __syncthreads();
#pragma unroll
    for (int i = 0; i < 4; i++) {
        int s = S0 + sp0 + ty + i * 8;
        int c = c0 + tx;
        float sv = ts[tx][ty + i * 8];
        float pv = tp[tx][ty + i * 8] + lev[lv * C_ + c];
        size_t idx = ((size_t)(b * LQ_ + s)) * C_ + c;
        x[idx]     = sv;
        xbf[idx]   = __float2bfloat16(sv);
        posbf[idx] = __float2bfloat16(pv);
        qbf[idx]   = __float2bfloat16(sv + pv);
    }
}

// ---------- bf16 MFMA GEMM (staged 128x128): out = A[M,K] @ W^T + bias ----------
template<bool RELU, bool BF16OUT>
__global__ __launch_bounds__(256) void k_gemm_mfma(
    const __hip_bfloat16* __restrict__ A,
    const __hip_bfloat16* __restrict__ Wt,
    const float* __restrict__ bias,
    void* __restrict__ Co,
    int M, int N, int K)
{
    __shared__ char As[128 * 128];
    __shared__ char Bs[128 * 128];
    int t = threadIdx.x, w = t >> 6, lane = t & 63;
    int m0 = blockIdx.x * 128, n0 = blockIdx.y * 128;
    int wm = w >> 1, wn = w & 1;

    f32x4 acc[4][4] = {};

    int rowoff  = lane >> 3;
    int colswz  = ((lane & 7) ^ (lane >> 3)) << 3;

    for (int kt = 0; kt < K; kt += 64) {
#pragma unroll
        for (int j = 0; j < 4; j++) {
            int rowbase = w * 32 + j * 8;
            const __hip_bfloat16* srcA = A  + (size_t)(m0 + rowbase + rowoff) * K + kt + colswz;
            const __hip_bfloat16* srcB = Wt + (size_t)(n0 + rowbase + rowoff) * K + kt + colswz;
            __builtin_amdgcn_global_load_lds(
                (const AS1 void*)srcA, (AS3 void*)(As + rowbase * 128), 16, 0, 0);
            __builtin_amdgcn_global_load_lds(
                (const AS1 void*)srcB, (AS3 void*)(Bs + rowbase * 128), 16, 0, 0);
        }
        __syncthreads();
#pragma unroll
        for (int k0 = 0; k0 < 64; k0 += 32) {
            int kb = k0 * 2 + (lane >> 4) * 16;
            bf16x8 af[4], bfr[4];
#pragma unroll
            for (int mi = 0; mi < 4; mi++) {
                int r = wm * 64 + mi * 16 + (lane & 15);
                s16x8 raw = *(const s16x8*)(As + r * 128 + (kb ^ ((r & 7) << 4)));
                af[mi] = __builtin_bit_cast(bf16x8, raw);
            }
#pragma unroll
            for (int ni = 0; ni < 4; ni++) {
                int r = wn * 64 + ni * 16 + (lane & 15);
                s16x8 raw = *(const s16x8*)(Bs + r * 128 + (kb ^ ((r & 7) << 4)));
                bfr[ni] = __builtin_bit_cast(bf16x8, raw);
            }
#pragma unroll
            for (int mi = 0; mi < 4; mi++)
#pragma unroll
                for (int ni = 0; ni < 4; ni++)
                    acc[mi][ni] = __builtin_amdgcn_mfma_f32_16x16x32_bf16(
                        af[mi], bfr[ni], acc[mi][ni], 0, 0, 0);
        }
        __syncthreads();
    }

#pragma unroll
    for (int ni = 0; ni < 4; ni++) {
        int col = n0 + wn * 64 + ni * 16 + (lane & 15);
        float bb = bias[col];
#pragma unroll
        for (int mi = 0; mi < 4; mi++) {
            int row = m0 + wm * 64 + mi * 16 + ((lane >> 4) << 2);
#pragma unroll
            for (int r = 0; r < 4; r++) {
                float v = acc[mi][ni][r] + bb;
                if (RELU) v = fmaxf(v, 0.f);
                if (BF16OUT)
                    ((__hip_bfloat16*)Co)[(size_t)(row + r) * N + col] = __float2bfloat16(v);
                else
                    ((float*)Co)[(size_t)(row + r) * N + col] = v;
            }
        }
    }
}

// ---------- merged q-GEMM: [off | attn] = q @ [Woff|Wattn] (N=384) ----------
__global__ __launch_bounds__(256) void k_gemm_qa(
    const __hip_bfloat16* __restrict__ A,     // [M,256]
    const __hip_bfloat16* __restrict__ Wq,    // [384,256]
    const float* __restrict__ boff, const float* __restrict__ battn,
    __half* __restrict__ offh, float* __restrict__ attb, int M)
{
    constexpr int K = 256;
    __shared__ char As[128 * 128];
    __shared__ char Bs[128 * 128];
    int t = threadIdx.x, w = t >> 6, lane = t & 63;
    int m0 = blockIdx.x * 128, n0 = blockIdx.y * 128;
    int wm = w >> 1, wn = w & 1;

    f32x4 acc[4][4] = {};
    int rowoff  = lane >> 3;
    int colswz  = ((lane & 7) ^ (lane >> 3)) << 3;

    for (int kt = 0; kt < K; kt += 64) {
#pragma unroll
        for (int j = 0; j < 4; j++) {
            int rowbase = w * 32 + j * 8;
            const __hip_bfloat16* srcA = A  + (size_t)(m0 + rowbase + rowoff) * K + kt + colswz;
            const __hip_bfloat16* srcB = Wq + (size_t)(n0 + rowbase + rowoff) * K + kt + colswz;
            __builtin_amdgcn_global_load_lds(
                (const AS1 void*)srcA, (AS3 void*)(As + rowbase * 128), 16, 0, 0);
            __builtin_amdgcn_global_load_lds(
                (const AS1 void*)srcB, (AS3 void*)(Bs + rowbase * 128), 16, 0, 0);
        }
        __syncthreads();
#pragma unroll
        for (int k0 = 0; k0 < 64; k0 += 32) {
            int kb = k0 * 2 + (lane >> 4) * 16;
            bf16x8 af[4], bfr[4];
#pragma unroll
            for (int mi = 0; mi < 4; mi++) {
                int r = wm * 64 + mi * 16 + (lane & 15);
                s16x8 raw = *(const s16x8*)(As + r * 128 + (kb ^ ((r & 7) << 4)));
                af[mi] = __builtin_bit_cast(bf16x8, raw);
            }
#pragma unroll
            for (int ni = 0; ni < 4; ni++) {
                int r = wn * 64 + ni * 16 + (lane & 15);
                s16x8 raw = *(const s16x8*)(Bs + r * 128 + (kb ^ ((r & 7) << 4)));
                bfr[ni] = __builtin_bit_cast(bf16x8, raw);
            }
#pragma unroll
            for (int mi = 0; mi < 4; mi++)
#pragma unroll
                for (int ni = 0; ni < 4; ni++)
                    acc[mi][ni] = __builtin_amdgcn_mfma_f32_16x16x32_bf16(
                        af[mi], bfr[ni], acc[mi][ni], 0, 0, 0);
        }
        __syncthreads();
    }

    if (blockIdx.y == 2) {
#pragma unroll
        for (int ni = 0; ni < 4; ni++) {
            int col = wn * 64 + ni * 16 + (lane & 15);
            float bb = battn[col];
#pragma unroll
            for (int mi = 0; mi < 4; mi++) {
                int row = m0 + wm * 64 + mi * 16 + ((lane >> 4) << 2);
#pragma unroll
                for (int r = 0; r < 4; r++)
                    attb[(size_t)(row + r) * 128 + col] = acc[mi][ni][r] + bb;
            }
        }
    } else {
#pragma unroll
        for (int ni = 0; ni < 4; ni++) {
            int col = n0 + wn * 64 + ni * 16 + (lane & 15);
            float bb = boff[col];
#pragma unroll
            for (int mi = 0; mi < 4; mi++) {
                int row = m0 + wm * 64 + mi * 16 + ((lane >> 4) << 2);
#pragma unroll
                for (int r = 0; r < 4; r++)
                    offh[(size_t)(row + r) * 256 + col] = __float2half(acc[mi][ni][r] + bb);
            }
        }
    }
}

// ---------- stage 64x256 bf16 tile into swizzled LDS (256 threads) ----------
static __device__ __forceinline__ void stage_x64(
    const __hip_bfloat16* __restrict__ src, int m0, char* xs, int w, int lane)
{
    int r  = lane >> 5;                 // 0/1
    int gl = lane & 31;                 // 16B granule in row
#pragma unroll
    for (int j = 0; j < 8; j++) {
        int row = (j * 4 + w) * 2 + r;
        int gsw = gl ^ (row & 7);
        const __hip_bfloat16* s = src + (size_t)(m0 + row) * 256 + gsw * 8;
        __builtin_amdgcn_global_load_lds(
            (const AS1 void*)s, (AS3 void*)(xs + (j * 4 + w) * 1024), 16, 0, 0);
    }
}

// ================== LN epilogue (BM=64, 4 waves x 64 cols) ==========
template<bool WRITE_Q>
static __device__ __forceinline__ void ln_epilogue64(
    f32x4 (&acc)[4][4], int m0, int w, int lane,
    const float* bias, float* xio, __hip_bfloat16* xbf,
    const float* g, const float* beta,
    const __hip_bfloat16* posb, __hip_bfloat16* qout,
    float (*sred1)[4], float (*sred2)[4])
{
    int cl = lane & 15;
    int rg = (lane >> 4) << 2;
    float bcol[4], gcol[4], btcol[4];
#pragma unroll
    for (int ni = 0; ni < 4; ni++) {
        int col = w * 64 + ni * 16 + cl;
        bcol[ni]  = bias[col];
        gcol[ni]  = g[col];
        btcol[ni] = beta[col];
    }

#pragma unroll
    for (int mi = 0; mi < 4; mi++)
#pragma unroll
    for (int r = 0; r < 4; r++) {
        int lr  = mi * 16 + rg + r;
        int row = m0 + lr;
        float s = 0.f;
#pragma unroll
        for (int ni = 0; ni < 4; ni++) {
            int col = w * 64 + ni * 16 + cl;
            float v = acc[mi][ni][r] + bcol[ni] + xio[(size_t)row * 256 + col];
            acc[mi][ni][r] = v;
            s += v;
        }
        s += __shfl_xor(s, 1); s += __shfl_xor(s, 2);
        s += __shfl_xor(s, 4); s += __shfl_xor(s, 8);
        if (cl == 0) sred1[lr][w] = s;
    }
    __syncthreads();

    float mu[4][4];
#pragma unroll
    for (int mi = 0; mi < 4; mi++)
#pragma unroll
    for (int r = 0; r < 4; r++) {
        int lr = mi * 16 + rg + r;
        mu[mi][r] = (sred1[lr][0] + sred1[lr][1] + sred1[lr][2] + sred1[lr][3]) * (1.f / 256.f);
        float s2 = 0.f;
#pragma unroll
        for (int ni = 0; ni < 4; ni++) {
            float d = acc[mi][ni][r] - mu[mi][r];
            s2 += d * d;
        }
        s2 += __shfl_xor(s2, 1); s2 += __shfl_xor(s2, 2);
        s2 += __shfl_xor(s2, 4); s2 += __shfl_xor(s2, 8);
        if (cl == 0) sred2[lr][w] = s2;
    }
    __syncthreads();

#pragma unroll
    for (int mi = 0; mi < 4; mi++)
#pragma unroll
    for (int r = 0; r < 4; r++) {
        int lr  = mi * 16 + rg + r;
        int row = m0 + lr;
        float var = (sred2[lr][0] + sred2[lr][1] + sred2[lr][2] + sred2[lr][3]) * (1.f / 256.f);
        float rstd = rsqrtf(var + 1e-5f);
#pragma unroll
        for (int ni = 0; ni < 4; ni++) {
            int col = w * 64 + ni * 16 + cl;
            size_t idx = (size_t)row * 256 + col;
            float o = (acc[mi][ni][r] - mu[mi][r]) * rstd * gcol[ni] + btcol[ni];
            xio[idx] = o;
            xbf[idx] = __float2bfloat16(o);
            if (WRITE_Q)
                qout[idx] = __float2bfloat16(o + bf2f(__builtin_bit_cast(unsigned short, posb[idx])));
        }
    }
}

// ---------- generic direct-B GEMM (K=256): BM=64, B frags from global (L2-hot) ----------
template<bool RELU>
__global__ __launch_bounds__(256) void k_gemm_direct(
    const __hip_bfloat16* __restrict__ A,     // [M,256]
    const __hip_bfloat16* __restrict__ Wt,    // [N,256]
    const float* __restrict__ bias,           // [N]
    __hip_bfloat16* __restrict__ out, int N)  // [M,N]
{
    __shared__ char xs[64 * 512];
    int t = threadIdx.x, w = t >> 6, lane = t & 63;
    int m0 = blockIdx.x * 64, n0 = blockIdx.y * 256;

    stage_x64(A, m0, xs, w, lane);
    asm volatile("s_waitcnt vmcnt(0)" ::: "memory");
    __builtin_amdgcn_s_barrier();

    f32x4 acc[4][4] = {};
#pragma unroll
    for (int k0 = 0; k0 < 256; k0 += 32) {
        int kb = k0 * 2 + (lane >> 4) * 16;
        bf16x8 af[4], bw[4];
#pragma unroll
        for (int mi = 0; mi < 4; mi++) {
            int r = mi * 16 + (lane & 15);
            s16x8 raw = *(const s16x8*)(xs + r * 512 + (kb ^ ((r & 7) << 4)));
            af[mi] = __builtin_bit_cast(bf16x8, raw);
        }
#pragma unroll
        for (int ni = 0; ni < 4; ni++) {
            int col = n0 + w * 64 + ni * 16 + (lane & 15);
            bw[ni] = *(const bf16x8*)(Wt + (size_t)col * 256 + k0 + (lane >> 4) * 8);
        }
#pragma unroll
        for (int mi = 0; mi < 4; mi++)
#pragma unroll
            for (int ni = 0; ni < 4; ni++)
                acc[mi][ni] = __builtin_amdgcn_mfma_f32_16x16x32_bf16(
                    af[mi], bw[ni], acc[mi][ni], 0, 0, 0);
    }

#pragma unroll
    for (int ni = 0; ni < 4; ni++) {
        int col = n0 + w * 64 + ni * 16 + (lane & 15);
        float bb = bias[col];
#pragma unroll
        for (int mi = 0; mi < 4; mi++) {
            int row = m0 + mi * 16 + ((lane >> 4) << 2);
#pragma unroll
            for (int r = 0; r < 4; r++) {
                float v = acc[mi][ni][r] + bb;
                if (RELU) v = fmaxf(v, 0.f);
                out[(size_t)(row + r) * N + col] = __float2bfloat16(v);
            }
        }
    }
}

// ---------- out-proj + LN: BM=64, K=256, B direct ----------
template<bool WRITE_Q>
__global__ __launch_bounds__(256) void k_out(
    const __hip_bfloat16* __restrict__ A,     // [M,256] sampled
    const __hip_bfloat16* __restrict__ Wt,    // [256,256]
    const float* __restrict__ bias,
    float* __restrict__ xio, __hip_bfloat16* __restrict__ xbf,
    const float* __restrict__ g, const float* __restrict__ beta,
    const __hip_bfloat16* __restrict__ posb, __hip_bfloat16* __restrict__ qout)
{
    __shared__ char xs[64 * 512];
    __shared__ float sred1[64][4];
    __shared__ float sred2[64][4];

    int t = threadIdx.x, w = t >> 6, lane = t & 63;
    int m0 = blockIdx.x * 64;

    stage_x64(A, m0, xs, w, lane);
    asm volatile("s_waitcnt vmcnt(0)" ::: "memory");
    __builtin_amdgcn_s_barrier();

    f32x4 acc[4][4] = {};
#pragma unroll
    for (int k0 = 0; k0 < 256; k0 += 32) {
        int kb = k0 * 2 + (lane >> 4) * 16;
        bf16x8 af[4], bw[4];
#pragma unroll
        for (int mi = 0; mi < 4; mi++) {
            int r = mi * 16 + (lane & 15);
            s16x8 raw = *(const s16x8*)(xs + r * 512 + (kb ^ ((r & 7) << 4)));
            af[mi] = __builtin_bit_cast(bf16x8, raw);
        }
#pragma unroll
        for (int ni = 0; ni < 4; ni++) {
            int col = w * 64 + ni * 16 + (lane & 15);
            bw[ni] = *(const bf16x8*)(Wt + (size_t)col * 256 + k0 + (lane >> 4) * 8);
        }
#pragma unroll
        for (int mi = 0; mi < 4; mi++)
#pragma unroll
            for (int ni = 0; ni < 4; ni++)
                acc[mi][ni] = __builtin_amdgcn_mfma_f32_16x16x32_bf16(
                    af[mi], bw[ni], acc[mi][ni], 0, 0, 0);
    }
    __syncthreads();

    ln_epilogue64<WRITE_Q>(acc, m0, w, lane, bias, xio, xbf, g, beta, posb, qout,
                           sred1, sred2);
}

// ---------- FF2 GEMM (N=256) + bias + residual + LN, BM=128, full A+B dbuf ----------
template<bool WRITE_Q>
__global__ __launch_bounds__(512) void k_gemm_ln(
    const __hip_bfloat16* __restrict__ A,    // [M,K]
    const __hip_bfloat16* __restrict__ Wt,   // [256,K]
    const float* __restrict__ bias,
    float* __restrict__ xio,
    __hip_bfloat16* __restrict__ xbf,
    const float* __restrict__ g, const float* __restrict__ beta,
    const __hip_bfloat16* __restrict__ posb,
    __hip_bfloat16* __restrict__ qout,
    int M, int K)
{
    __shared__ char As[2][128 * 128];
    __shared__ char Bs[2][256 * 128];
    __shared__ float sred1[128][4];
    __shared__ float sred2[128][4];

    int t = threadIdx.x, w = t >> 6, lane = t & 63;
    int m0 = blockIdx.x * 128;
    int wm = w >> 2, wn = w & 3;

    f32x4 acc[4][4] = {};

    int rowoff  = lane >> 3;
    int colswz  = ((lane & 7) ^ rowoff) << 3;

    auto STAGE = [&](char* Ab, char* Bb, int kt) {
#pragma unroll
        for (int j = 0; j < 2; j++) {
            int rowbase = w * 16 + j * 8;
            const __hip_bfloat16* srcA = A + (size_t)(m0 + rowbase + rowoff) * K + kt + colswz;
            __builtin_amdgcn_global_load_lds(
                (const AS1 void*)srcA, (AS3 void*)(Ab + rowbase * 128), 16, 0, 0);
        }
#pragma unroll
        for (int j = 0; j < 4; j++) {
            int rowbase = w * 32 + j * 8;
            const __hip_bfloat16* srcB = Wt + (size_t)(rowbase + rowoff) * K + kt + colswz;
            __builtin_amdgcn_global_load_lds(
                (const AS1 void*)srcB, (AS3 void*)(Bb + rowbase * 128), 16, 0, 0);
        }
    };

    STAGE(As[0], Bs[0], 0);
    asm volatile("s_waitcnt vmcnt(0)" ::: "memory");
    __builtin_amdgcn_s_barrier();

    const int nt = K >> 6;
    int cur = 0;
    for (int tt = 0; tt < nt; ++tt) {
        if (tt + 1 < nt) STAGE(As[cur ^ 1], Bs[cur ^ 1], (tt + 1) << 6);
        const char* Ab = As[cur];
        const char* Bb = Bs[cur];
#pragma unroll
        for (int k0 = 0; k0 < 64; k0 += 32) {
            int kb = k0 * 2 + (lane >> 4) * 16;
            bf16x8 af[4], bfr[4];
#pragma unroll
            for (int mi = 0; mi < 4; mi++) {
                int r = wm * 64 + mi * 16 + (lane & 15);
                s16x8 raw = *(const s16x8*)(Ab + r * 128 + (kb ^ ((r & 7) << 4)));
                af[mi] = __builtin_bit_cast(bf16x8, raw);
            }
#pragma unroll
            for (int ni = 0; ni < 4; ni++) {
                int r = wn * 64 + ni * 16 + (lane & 15);
                s16x8 raw = *(const s16x8*)(Bb + r * 128 + (kb ^ ((r & 7) << 4)));
                bfr[ni] = __builtin_bit_cast(bf16x8, raw);
            }
#pragma unroll
            for (int mi = 0; mi < 4; mi++)
#pragma unroll
                for (int ni = 0; ni < 4; ni++)
                    acc[mi][ni] = __builtin_amdgcn_mfma_f32_16x16x32_bf16(
                        af[mi], bfr[ni], acc[mi][ni], 0, 0, 0);
        }
        asm volatile("s_waitcnt vmcnt(0)" ::: "memory");
        __builtin_amdgcn_s_barrier();
        cur ^= 1;
    }

    // ---- fused bias + residual + LN epilogue ----
    int cl = lane & 15;
    int rg = (lane >> 4) << 2;
    float bcol[4], gcol[4], btcol[4];
#pragma unroll
    for (int ni = 0; ni < 4; ni++) {
        int col = wn * 64 + ni * 16 + cl;
        bcol[ni]  = bias[col];
        gcol[ni]  = g[col];
        btcol[ni] = beta[col];
    }

#pragma unroll
    for (int mi = 0; mi < 4; mi++)
#pragma unroll
    for (int r = 0; r < 4; r++) {
        int lr  = wm * 64 + mi * 16 + rg + r;
        int row = m0 + lr;
        float s = 0.f;
#pragma unroll
        for (int ni = 0; ni < 4; ni++) {
            int col = wn * 64 + ni * 16 + cl;
            float v = acc[mi][ni][r] + bcol[ni] + xio[(size_t)row * 256 + col];
            acc[mi][ni][r] = v;
            s += v;
        }
        s += __shfl_xor(s, 1); s += __shfl_xor(s, 2);
        s += __shfl_xor(s, 4); s += __shfl_xor(s, 8);
        if (cl == 0) sred1[lr][wn] = s;
    }
    __syncthreads();

    float mu[4][4];
#pragma unroll
    for (int mi = 0; mi < 4; mi++)
#pragma unroll
    for (int r = 0; r < 4; r++) {
        int lr = wm * 64 + mi * 16 + rg + r;
        mu[mi][r] = (sred1[lr][0] + sred1[lr][1] + sred1[lr][2] + sred1[lr][3]) * (1.f / 256.f);
        float s2 = 0.f;
#pragma unroll
        for (int ni = 0; ni < 4; ni++) {
            float d = acc[mi][ni][r] - mu[mi][r];
            s2 += d * d;
        }
        s2 += __shfl_xor(s2, 1); s2 += __shfl_xor(s2, 2);
        s2 += __shfl_xor(s2, 4); s2 += __shfl_xor(s2, 8);
        if (cl == 0) sred2[lr][wn] = s2;
    }
    __syncthreads();

#pragma unroll
    for (int mi = 0; mi < 4; mi++)
#pragma unroll
    for (int r = 0; r < 4; r++) {
        int lr  = wm * 64 + mi * 16 + rg + r;
        int row = m0 + lr;
        float var = (sred2[lr][0] + sred2[lr][1] + sred2[lr][2] + sred2[lr][3]) * (1.f / 256.f);
        float rstd = rsqrtf(var + 1e-5f);
#pragma unroll
        for (int ni = 0; ni < 4; ni++) {
            int col = wn * 64 + ni * 16 + cl;
            size_t idx = (size_t)row * 256 + col;
            float o = (acc[mi][ni][r] - mu[mi][r]) * rstd * gcol[ni] + btcol[ni];
            xio[idx] = o;
            xbf[idx] = __float2bfloat16(o);
            if (WRITE_Q)
                qout[idx] = __float2bfloat16(o + bf2f(__builtin_bit_cast(unsigned short, posb[idx])));
        }
    }
}

// ---------- deformable sampling v4 ----------
__global__ __launch_bounds__(256) void k_sample4(const __hip_bfloat16* __restrict__ val,
                                                 const __half* __restrict__ offh,
                                                 const float* __restrict__ logits,
                                                 __hip_bfloat16* __restrict__ out)
{
    __shared__ int2 sIW[4 * 64 * 17];

    int t  = threadIdx.x;
    int qb = blockIdx.x;

#pragma unroll
    for (int it = 0; it < 4; it++) {
        int item = t + it * 256;
        int qi = item >> 7;
        int pt = item & 127;
        int bs = qb * 8 + qi;
        int b  = bs / LQ_;
        int s  = bs % LQ_;
        int h  = pt >> 4, lv = (pt >> 2) & 3;

        float lg = logits[(size_t)bs * 128 + pt];
        float mx = lg;
#pragma unroll
        for (int m = 1; m < 16; m <<= 1) mx = fmaxf(mx, __shfl_xor(mx, m));
        float ex = __expf(lg - mx);
        float sm = ex;
#pragma unroll
        for (int m = 1; m < 16; m <<= 1) sm += __shfl_xor(sm, m);
        float aw = ex / sm;

        int p0, Wq;
        if (s < 16384)      { p0 = s;         Wq = 128; }
        else if (s < 20480) { p0 = s - 16384; Wq = 64;  }
        else if (s < 21504) { p0 = s - 20480; Wq = 32;  }
        else                { p0 = s - 21504; Wq = 16;  }
        float invWq = 1.f / (float)Wq;
        float refx = ((p0 % Wq) + 0.5f) * invWq;
        float refy = ((p0 / Wq) + 0.5f) * invWq;

        int W  = 128 >> lv;
        int S0 = (65536 - (65536 >> (2 * lv))) / 3;
        float fW = (float)W;

        __half2 o2 = ((const __half2*)(offh + (size_t)bs * 256))[pt];
        float ox = __low2float(o2), oy = __high2float(o2);
        float xx = refx * fW + ox - 0.5f;
        float yy = refy * fW + oy - 0.5f;
        float x0f = floorf(xx), y0f = floorf(yy);
        float wx = xx - x0f, wy = yy - y0f;
        int x0 = (int)x0f, y0 = (int)y0f;
        int x1 = x0 + 1, y1 = y0 + 1;
        bool vx0 = (x0 >= 0) & (x0 < W), vx1 = (x1 >= 0) & (x1 < W);
        bool vy0 = (y0 >= 0) & (y0 < W), vy1 = (y1 >= 0) & (y1 < W);
        int cx0 = min(max(x0, 0), W - 1), cx1 = min(max(x1, 0), W - 1);
        int cy0 = min(max(y0, 0), W - 1), cy1 = min(max(y1, 0), W - 1);

        int rowbase = (b * LQ_ + S0) * C_ + h * DH_;
        int g  = item >> 4;
        int pj = pt & 15;
        int i00 = (rowbase + (cy0 * W + cx0) * C_) * 2;
        int i10 = (rowbase + (cy0 * W + cx1) * C_) * 2;
        int i01 = (rowbase + (cy1 * W + cx0) * C_) * 2;
        int i11 = (rowbase + (cy1 * W + cx1) * C_) * 2;
        float w00 = aw * (1.f - wx) * (1.f - wy) * ((vx0 & vy0) ? 1.f : 0.f);
        float w10 = aw * wx * (1.f - wy) * ((vx1 & vy0) ? 1.f : 0.f);
        float w01 = aw * (1.f - wx) * wy * ((vx0 & vy1) ? 1.f : 0.f);
        float w11 = aw * wx * wy * ((vx1 & vy1) ? 1.f : 0.f);
        sIW[(0 * 64 + g) * 17 + pj] = make_int2(i00, __float_as_int(w00));
        sIW[(1 * 64 + g) * 17 + pj] = make_int2(i10, __float_as_int(w10));
        sIW[(2 * 64 + g) * 17 + pj] = make_int2(i01, __float_as_int(w01));
        sIW[(3 * 64 + g) * 17 + pj] = make_int2(i11, __float_as_int(w11));
    }
    __syncthreads();

    {
        int g  = t >> 2;
        int dq = t & 3;
        int bs = qb * 8 + (g >> 3);
        int h  = g & 7;
        int dbyte = dq * 16;

        const char* vbase = (const char*)val;
        float a0 = 0.f, a1 = 0.f, a2 = 0.f, a3 = 0.f;
        float a4 = 0.f, a5 = 0.f, a6 = 0.f, a7 = 0.f;
#pragma unroll
        for (int j = 0; j < 16; j++) {
#pragma unroll
            for (int k = 0; k < 4; k++) {
                int2 iw = sIW[(k * 64 + g) * 17 + j];
                float w = __int_as_float(iw.y);
                uint4 u = *(const uint4*)(vbase + iw.x + dbyte);
                a0 = fmaf(w, __builtin_bit_cast(float, u.x << 16), a0);
                a1 = fmaf(w, __builtin_bit_cast(float, u.x & 0xffff0000u), a1);
                a2 = fmaf(w, __builtin_bit_cast(float, u.y << 16), a2);
                a3 = fmaf(w, __builtin_bit_cast(float, u.y & 0xffff0000u), a3);
                a4 = fmaf(w, __builtin_bit_cast(float, u.z << 16), a4);
                a5 = fmaf(w, __builtin_bit_cast(float, u.z & 0xffff0000u), a5);
                a6 = fmaf(w, __builtin_bit_cast(float, u.w << 16), a6);
                a7 = fmaf(w, __builtin_bit_cast(float, u.w & 0xffff0000u), a7);
            }
        }
        uint4 o;
        o.x = (unsigned)f2bf(a0) | ((unsigned)f2bf(a1) << 16);
        o.y = (unsigned)f2bf(a2) | ((unsigned)f2bf(a3) << 16);
        o.z = (unsigned)f2bf(a4) | ((unsigned)f2bf(a5) << 16);
        o.w = (unsigned)f2bf(a6) | ((unsigned)f2bf(a7) << 16);
        *(uint4*)((char*)out + (size_t)bs * 512 + h * 64 + dbyte) = o;
    }
}

// ---------- driver ----------
extern "C" void kernel_launch(void* const* d_in, const int* in_sizes, int n_in,
                              void* d_out, int out_size, void* d_ws, size_t ws_size,
                              hipStream_t stream)
{
    const float* src_[4] = {(const float*)d_in[0], (const float*)d_in[2],
                            (const float*)d_in[4], (const float*)d_in[6]};
    const float* pos_[4] = {(const float*)d_in[1], (const float*)d_in[3],
                            (const float*)d_in[5], (const float*)d_in[7]};
    const float* lev   = (const float*)d_in[8];
    const float* Woff  = (const float*)d_in[9];
    const float* boff  = (const float*)d_in[10];
    const float* Wattn = (const float*)d_in[11];
    const float* battn = (const float*)d_in[12];
    const float* Wval  = (const float*)d_in[13];
    const float* bval  = (const float*)d_in[14];
    const float* Wout  = (const float*)d_in[15];
    const float* bout  = (const float*)d_in[16];
    const float* g1    = (const float*)d_in[17];
    const float* b1    = (const float*)d_in[18];
    const float* Wff1  = (const float*)d_in[19];
    const float* bff1  = (const float*)d_in[20];
    const float* Wff2  = (const float*)d_in[21];
    const float* bff2  = (const float*)d_in[22];
    const float* g2    = (const float*)d_in[23];
    const float* b2    = (const float*)d_in[24];

    float* x = (float*)d_out;                       // persistent hidden state (fp32)
    size_t MC = (size_t)M_ * C_;                    // 11,141,120

    // layout (each mid segment = M*512 bytes):
    // pos | q | x_bf | offh(f16 M*256) | attb(f32 M*128) | val_bf | pad | weights
    // ffh [M,1024] bf16 aliases offh..pad exactly (4 x M*512 B).
    __hip_bfloat16* pos_bf = (__hip_bfloat16*)d_ws;
    __hip_bfloat16* q_bf   = pos_bf + MC;
    __hip_bfloat16* x_bf   = q_bf + MC;
    __half* offh           = (__half*)(x_bf + MC);            // M*256 f16
    float*  attb           = (float*)(offh + MC);             // M*128 f32
    __hip_bfloat16* val_bf = (__hip_bfloat16*)(attb + (size_t)M_ * 128);
    __hip_bfloat16* pad_bf = val_bf + MC;                     // ffh tail
    __hip_bfloat16* ffh_bf = (__hip_bfloat16*)offh;           // [M,1024] alias
    __hip_bfloat16* wbf    = pad_bf + MC;

    __hip_bfloat16* wq    = wbf;                        // 6*384*256
    __hip_bfloat16* wvalt = wq    + 6 * 98304;
    __hip_bfloat16* woutt = wvalt + 6 * 65536;
    __hip_bfloat16* wff1t = woutt + 6 * 65536;
    __hip_bfloat16* wff2t = wff1t + 6 * 262144;

    dim3 blk(256);
    dim3 tblk(32, 8);

    k_wt<<<dim3(8, 8, 6),  tblk, 0, stream>>>(Woff,  wq,               256, 256,  98304);
    k_wt<<<dim3(4, 8, 6),  tblk, 0, stream>>>(Wattn, wq + 256 * 256,   256, 128,  98304);
    k_wt<<<dim3(8, 8, 6),  tblk, 0, stream>>>(Wval,  wvalt,            256, 256,  65536);
    k_wt<<<dim3(8, 8, 6),  tblk, 0, stream>>>(Wout,  woutt,            256, 256,  65536);
    k_wt<<<dim3(32, 8, 6), tblk, 0, stream>>>(Wff1,  wff1t,            256, 1024, 262144);
    k_wt<<<dim3(8, 32, 6), tblk, 0, stream>>>(Wff2,  wff2t,            1024, 256, 262144);

    k_assemble2<<<10880, blk, 0, stream>>>(
        src_[0], src_[1], src_[2], src_[3],
        pos_[0], pos_[1], pos_[2], pos_[3], lev, x, x_bf, pos_bf, q_bf);

    for (int l = 0; l < 6; l++) {
        // off (f16) + attn logits (f32) in one GEMM (N=384)
        k_gemm_qa<<<dim3(M_ / 128, 3), blk, 0, stream>>>(
            q_bf, wq + (size_t)l * 98304, boff + l * 256, battn + l * 128,
            offh, attb, M_);

        // val = x @ Wval + bval  [M,256] bf16  (direct-B, K=256)
        k_gemm_direct<false><<<dim3(M_ / 64, 1), blk, 0, stream>>>(
            x_bf, wvalt + (size_t)l * 65536, bval + l * 256, val_bf, 256);

        // deformable sampling (softmax fused) -> q_bf
        k_sample4<<<M_ / 8, blk, 0, stream>>>(val_bf, offh, attb, q_bf);

        // out-proj + bias + residual + LN -> x, x_bf  (BM=64, direct-B, K=256)
        k_out<false><<<M_ / 64, blk, 0, stream>>>(
            q_bf, woutt + (size_t)l * 65536, bout + l * 256,
            x, x_bf, g1 + l * 256, b1 + l * 256, nullptr, nullptr);

        // FF1: ffh = relu(x@W1+b1)  (staged 128x128 tiles)
        k_gemm_mfma<true, true><<<dim3(M_ / 128, 8), blk, 0, stream>>>(
            x_bf, wff1t + (size_t)l * 262144, bff1 + l * DFF_, ffh_bf, M_, DFF_, C_);

        // FF2 + residual + LN (+ q for next layer)  (full A+B dbuf)
        if (l < 5)
            k_gemm_ln<true><<<M_ / 128, 512, 0, stream>>>(
                ffh_bf, wff2t + (size_t)l * 262144, bff2 + l * C_,
                x, x_bf, g2 + l * 256, b2 + l * 256, pos_bf, q_bf, M_, DFF_);
        else
            k_gemm_ln<false><<<M_ / 128, 512, 0, stream>>>(
                ffh_bf, wff2t + (size_t)l * 262144, bff2 + l * C_,
                x, x_bf, g2 + l * 256, b2 + l * 256, nullptr, nullptr, M_, DFF_);
    }
}

// Round 12
// 1875.760 us; speedup vs baseline: 1.1666x; 1.0030x over previous
//
#include <hip/hip_runtime.h>
#include <hip/hip_bf16.h>
#include <hip/hip_fp16.h>
#include <math.h>

namespace {
constexpr int B_   = 2;
constexpr int C_   = 256;
constexpr int NH_  = 8;
constexpr int DH_  = 32;
constexpr int NP_  = 4;
constexpr int DFF_ = 1024;
constexpr int LQ_  = 21760;
constexpr int M_   = B_ * LQ_;     // 43520
}

typedef __bf16  bf16x8 __attribute__((ext_vector_type(8)));
typedef short   s16x8  __attribute__((ext_vector_type(8)));
typedef float   f32x4  __attribute__((ext_vector_type(4)));

#define AS1 __attribute__((address_space(1)))
#define AS3 __attribute__((address_space(3)))

static __device__ __forceinline__ unsigned short f2bf(float f) {
    return __builtin_bit_cast(unsigned short, __float2bfloat16(f));
}
static __device__ __forceinline__ float bf2f(unsigned short u) {
    return __bfloat162float(__builtin_bit_cast(__hip_bfloat16, u));
}

// ---------- weight transpose + cvt: in [L][K][N] f32 -> out rows [N][K] bf16 ----------
__global__ void k_wt(const float* __restrict__ in, __hip_bfloat16* __restrict__ out,
                     int K, int N, int outStride)
{
    __shared__ float tile[32][33];
    int n0 = blockIdx.x * 32, k0 = blockIdx.y * 32;
    const float* inl = in + (size_t)blockIdx.z * K * N;
    __hip_bfloat16* outl = out + (size_t)blockIdx.z * outStride;
    for (int i = threadIdx.y; i < 32; i += 8)
        tile[i][threadIdx.x] = inl[(size_t)(k0 + i) * N + n0 + threadIdx.x];
    __syncthreads();
    for (int i = threadIdx.y; i < 32; i += 8)
        outl[(size_t)(n0 + i) * K + k0 + threadIdx.x] = __float2bfloat16(tile[threadIdx.x][i]);
}

// ---------- weight -> fragment-linear layout ----------
// in [L][K][N] f32 (k-major). out frag: out[((k/32)*N + col)*32 + g*8 + j] =
// in[(k0+g*8+j)*N + col]  -> a wave's 64 B-frag loads (16 cols x 4 granules)
// cover one contiguous 1KB block (perfectly coalesced, L2-hot).
__global__ void k_wt2(const float* __restrict__ in, __hip_bfloat16* __restrict__ out,
                      int K, int N, int outStride)
{
    __shared__ float tile[32][65];
    int col0 = blockIdx.x * 64;
    int k0   = blockIdx.y * 32;
    const float* inl = in + (size_t)blockIdx.z * K * N;
    __hip_bfloat16* outl = out + (size_t)blockIdx.z * outStride;
    int t = threadIdx.x;
#pragma unroll
    for (int p = 0; p < 8; p++) {
        int s = t + p * 256;
        tile[s >> 6][s & 63] = inl[(size_t)(k0 + (s >> 6)) * N + col0 + (s & 63)];
    }
    __syncthreads();
    size_t base = ((size_t)(k0 >> 5) * N + col0) * 32;
#pragma unroll
    for (int p = 0; p < 8; p++) {
        int s = t + p * 256;
        outl[base + s] = __float2bfloat16(tile[s & 31][(s >> 5) & 63]);
    }
}

// ---------- coalesced assemble via LDS transpose ----------
__global__ __launch_bounds__(256) void k_assemble2(
    const float* __restrict__ s0, const float* __restrict__ s1,
    const float* __restrict__ s2, const float* __restrict__ s3,
    const float* __restrict__ p0, const float* __restrict__ p1,
    const float* __restrict__ p2, const float* __restrict__ p3,
    const float* __restrict__ lev, float* __restrict__ x,
    __hip_bfloat16* __restrict__ xbf, __hip_bfloat16* __restrict__ posbf,
    __hip_bfloat16* __restrict__ qbf)
{
    int bid = blockIdx.x;
    int lv, rem, HW, S0;
    const float *sp, *pp;
    if (bid < 8192)       { lv = 0; rem = bid;         HW = 16384; S0 = 0;     sp = s0; pp = p0; }
    else if (bid < 10240) { lv = 1; rem = bid - 8192;  HW = 4096;  S0 = 16384; sp = s1; pp = p1; }
    else if (bid < 10752) { lv = 2; rem = bid - 10240; HW = 1024;  S0 = 20480; sp = s2; pp = p2; }
    else                  { lv = 3; rem = bid - 10752; HW = 256;   S0 = 21504; sp = s3; pp = p3; }
    int sptiles = HW >> 5;
    int spt = rem % sptiles;
    int ct  = (rem / sptiles) & 7;
    int b   = rem / (sptiles * 8);
    int sp0 = spt * 32, c0 = ct * 32;

    __shared__ float ts[32][33], tp[32][33];
    int tx = threadIdx.x & 31, ty = threadIdx.x >> 5;
#pragma unroll
    for (int i = 0; i < 4; i++) {
        int c = c0 + ty + i * 8;
        size_t si = ((size_t)(b * C_ + c)) * HW + sp0 + tx;
        ts[ty + i * 8][tx] = sp[si];
        tp[ty + i * 8][tx] = pp[si];
    }
    __syncthreads();
#pragma unroll
    for (int i = 0; i < 4; i++) {
        int s = S0 + sp0 + ty + i * 8;
        int c = c0 + tx;
        float sv = ts[tx][ty + i * 8];
        float pv = tp[tx][ty + i * 8] + lev[lv * C_ + c];
        size_t idx = ((size_t)(b * LQ_ + s)) * C_ + c;
        x[idx]     = sv;
        xbf[idx]   = __float2bfloat16(sv);
        posbf[idx] = __float2bfloat16(pv);
        qbf[idx]   = __float2bfloat16(sv + pv);
    }
}

// ---------- bf16 MFMA GEMM (staged 128x128): out = A[M,K] @ W^T + bias ----------
template<bool RELU, bool BF16OUT>
__global__ __launch_bounds__(256) void k_gemm_mfma(
    const __hip_bfloat16* __restrict__ A,
    const __hip_bfloat16* __restrict__ Wt,
    const float* __restrict__ bias,
    void* __restrict__ Co,
    int M, int N, int K)
{
    __shared__ char As[128 * 128];
    __shared__ char Bs[128 * 128];
    int t = threadIdx.x, w = t >> 6, lane = t & 63;
    int m0 = blockIdx.x * 128, n0 = blockIdx.y * 128;
    int wm = w >> 1, wn = w & 1;

    f32x4 acc[4][4] = {};

    int rowoff  = lane >> 3;
    int colswz  = ((lane & 7) ^ (lane >> 3)) << 3;

    for (int kt = 0; kt < K; kt += 64) {
#pragma unroll
        for (int j = 0; j < 4; j++) {
            int rowbase = w * 32 + j * 8;
            const __hip_bfloat16* srcA = A  + (size_t)(m0 + rowbase + rowoff) * K + kt + colswz;
            const __hip_bfloat16* srcB = Wt + (size_t)(n0 + rowbase + rowoff) * K + kt + colswz;
            __builtin_amdgcn_global_load_lds(
                (const AS1 void*)srcA, (AS3 void*)(As + rowbase * 128), 16, 0, 0);
            __builtin_amdgcn_global_load_lds(
                (const AS1 void*)srcB, (AS3 void*)(Bs + rowbase * 128), 16, 0, 0);
        }
        __syncthreads();
#pragma unroll
        for (int k0 = 0; k0 < 64; k0 += 32) {
            int kb = k0 * 2 + (lane >> 4) * 16;
            bf16x8 af[4], bfr[4];
#pragma unroll
            for (int mi = 0; mi < 4; mi++) {
                int r = wm * 64 + mi * 16 + (lane & 15);
                s16x8 raw = *(const s16x8*)(As + r * 128 + (kb ^ ((r & 7) << 4)));
                af[mi] = __builtin_bit_cast(bf16x8, raw);
            }
#pragma unroll
            for (int ni = 0; ni < 4; ni++) {
                int r = wn * 64 + ni * 16 + (lane & 15);
                s16x8 raw = *(const s16x8*)(Bs + r * 128 + (kb ^ ((r & 7) << 4)));
                bfr[ni] = __builtin_bit_cast(bf16x8, raw);
            }
#pragma unroll
            for (int mi = 0; mi < 4; mi++)
#pragma unroll
                for (int ni = 0; ni < 4; ni++)
                    acc[mi][ni] = __builtin_amdgcn_mfma_f32_16x16x32_bf16(
                        af[mi], bfr[ni], acc[mi][ni], 0, 0, 0);
        }
        __syncthreads();
    }

#pragma unroll
    for (int ni = 0; ni < 4; ni++) {
        int col = n0 + wn * 64 + ni * 16 + (lane & 15);
        float bb = bias[col];
#pragma unroll
        for (int mi = 0; mi < 4; mi++) {
            int row = m0 + wm * 64 + mi * 16 + ((lane >> 4) << 2);
#pragma unroll
            for (int r = 0; r < 4; r++) {
                float v = acc[mi][ni][r] + bb;
                if (RELU) v = fmaxf(v, 0.f);
                if (BF16OUT)
                    ((__hip_bfloat16*)Co)[(size_t)(row + r) * N + col] = __float2bfloat16(v);
                else
                    ((float*)Co)[(size_t)(row + r) * N + col] = v;
            }
        }
    }
}

// ---------- merged q-GEMM: [off | attn] = q @ [Woff|Wattn] (N=384) ----------
__global__ __launch_bounds__(256) void k_gemm_qa(
    const __hip_bfloat16* __restrict__ A,     // [M,256]
    const __hip_bfloat16* __restrict__ Wq,    // [384,256]
    const float* __restrict__ boff, const float* __restrict__ battn,
    __half* __restrict__ offh, float* __restrict__ attb, int M)
{
    constexpr int K = 256;
    __shared__ char As[128 * 128];
    __shared__ char Bs[128 * 128];
    int t = threadIdx.x, w = t >> 6, lane = t & 63;
    int m0 = blockIdx.x * 128, n0 = blockIdx.y * 128;
    int wm = w >> 1, wn = w & 1;

    f32x4 acc[4][4] = {};
    int rowoff  = lane >> 3;
    int colswz  = ((lane & 7) ^ (lane >> 3)) << 3;

    for (int kt = 0; kt < K; kt += 64) {
#pragma unroll
        for (int j = 0; j < 4; j++) {
            int rowbase = w * 32 + j * 8;
            const __hip_bfloat16* srcA = A  + (size_t)(m0 + rowbase + rowoff) * K + kt + colswz;
            const __hip_bfloat16* srcB = Wq + (size_t)(n0 + rowbase + rowoff) * K + kt + colswz;
            __builtin_amdgcn_global_load_lds(
                (const AS1 void*)srcA, (AS3 void*)(As + rowbase * 128), 16, 0, 0);
            __builtin_amdgcn_global_load_lds(
                (const AS1 void*)srcB, (AS3 void*)(Bs + rowbase * 128), 16, 0, 0);
        }
        __syncthreads();
#pragma unroll
        for (int k0 = 0; k0 < 64; k0 += 32) {
            int kb = k0 * 2 + (lane >> 4) * 16;
            bf16x8 af[4], bfr[4];
#pragma unroll
            for (int mi = 0; mi < 4; mi++) {
                int r = wm * 64 + mi * 16 + (lane & 15);
                s16x8 raw = *(const s16x8*)(As + r * 128 + (kb ^ ((r & 7) << 4)));
                af[mi] = __builtin_bit_cast(bf16x8, raw);
            }
#pragma unroll
            for (int ni = 0; ni < 4; ni++) {
                int r = wn * 64 + ni * 16 + (lane & 15);
                s16x8 raw = *(const s16x8*)(Bs + r * 128 + (kb ^ ((r & 7) << 4)));
                bfr[ni] = __builtin_bit_cast(bf16x8, raw);
            }
#pragma unroll
            for (int mi = 0; mi < 4; mi++)
#pragma unroll
                for (int ni = 0; ni < 4; ni++)
                    acc[mi][ni] = __builtin_amdgcn_mfma_f32_16x16x32_bf16(
                        af[mi], bfr[ni], acc[mi][ni], 0, 0, 0);
        }
        __syncthreads();
    }

    if (blockIdx.y == 2) {
#pragma unroll
        for (int ni = 0; ni < 4; ni++) {
            int col = wn * 64 + ni * 16 + (lane & 15);
            float bb = battn[col];
#pragma unroll
            for (int mi = 0; mi < 4; mi++) {
                int row = m0 + wm * 64 + mi * 16 + ((lane >> 4) << 2);
#pragma unroll
                for (int r = 0; r < 4; r++)
                    attb[(size_t)(row + r) * 128 + col] = acc[mi][ni][r] + bb;
            }
        }
    } else {
#pragma unroll
        for (int ni = 0; ni < 4; ni++) {
            int col = n0 + wn * 64 + ni * 16 + (lane & 15);
            float bb = boff[col];
#pragma unroll
            for (int mi = 0; mi < 4; mi++) {
                int row = m0 + wm * 64 + mi * 16 + ((lane >> 4) << 2);
#pragma unroll
                for (int r = 0; r < 4; r++)
                    offh[(size_t)(row + r) * 256 + col] = __float2half(acc[mi][ni][r] + bb);
            }
        }
    }
}

// ---------- GEMM (N=256) + bias + residual + LN; BM=128, A-only dbuf,
// B direct from FRAGMENT-LINEAR weights (coalesced 1KB/wave, L2-hot) ----------
template<bool WRITE_Q>
__global__ __launch_bounds__(512) void k_gemm_lnf(
    const __hip_bfloat16* __restrict__ A,    // [M,K]
    const __hip_bfloat16* __restrict__ Wf,   // frag: [(K/32)][256 cols][32]
    const float* __restrict__ bias,
    float* __restrict__ xio, __hip_bfloat16* __restrict__ xbf,
    const float* __restrict__ g, const float* __restrict__ beta,
    const __hip_bfloat16* __restrict__ posb, __hip_bfloat16* __restrict__ qout,
    int M, int K)
{
    __shared__ char As[2][128 * 128];
    __shared__ float sred1[128][4];
    __shared__ float sred2[128][4];

    int t = threadIdx.x, w = t >> 6, lane = t & 63;
    int m0 = blockIdx.x * 128;
    int wm = w >> 2, wn = w & 3;

    f32x4 acc[4][4] = {};
    int rowoff = lane >> 3;
    int colswz = ((lane & 7) ^ rowoff) << 3;
    int gq = lane >> 4;

    auto STAGE_A = [&](char* Ab, int kt) {
#pragma unroll
        for (int j = 0; j < 2; j++) {
            int rowbase = w * 16 + j * 8;
            const __hip_bfloat16* srcA = A + (size_t)(m0 + rowbase + rowoff) * K + kt + colswz;
            __builtin_amdgcn_global_load_lds(
                (const AS1 void*)srcA, (AS3 void*)(Ab + rowbase * 128), 16, 0, 0);
        }
    };

    STAGE_A(As[0], 0);
    asm volatile("s_waitcnt vmcnt(0)" ::: "memory");
    __builtin_amdgcn_s_barrier();

    const int nt = K >> 6;
    int cur = 0;
    for (int tt = 0; tt < nt; ++tt) {
        if (tt + 1 < nt) STAGE_A(As[cur ^ 1], (tt + 1) << 6);
        const char* Ab = As[cur];
#pragma unroll
        for (int k0 = 0; k0 < 64; k0 += 32) {
            int ks = tt * 2 + (k0 >> 5);
            int kb = k0 * 2 + gq * 16;
            bf16x8 af[4], bw[4];
#pragma unroll
            for (int mi = 0; mi < 4; mi++) {
                int r = wm * 64 + mi * 16 + (lane & 15);
                s16x8 raw = *(const s16x8*)(Ab + r * 128 + (kb ^ ((r & 7) << 4)));
                af[mi] = __builtin_bit_cast(bf16x8, raw);
            }
#pragma unroll
            for (int ni = 0; ni < 4; ni++) {
                int col = wn * 64 + ni * 16 + (lane & 15);
                bw[ni] = *(const bf16x8*)(Wf + (((size_t)ks * 256 + col) << 5) + (gq << 3));
            }
#pragma unroll
            for (int mi = 0; mi < 4; mi++)
#pragma unroll
                for (int ni = 0; ni < 4; ni++)
                    acc[mi][ni] = __builtin_amdgcn_mfma_f32_16x16x32_bf16(
                        af[mi], bw[ni], acc[mi][ni], 0, 0, 0);
        }
        asm volatile("s_waitcnt vmcnt(0)" ::: "memory");
        __builtin_amdgcn_s_barrier();
        cur ^= 1;
    }

    // ---- fused bias + residual + LN epilogue ----
    int cl = lane & 15;
    int rg = (lane >> 4) << 2;
    float bcol[4], gcol[4], btcol[4];
#pragma unroll
    for (int ni = 0; ni < 4; ni++) {
        int col = wn * 64 + ni * 16 + cl;
        bcol[ni]  = bias[col];
        gcol[ni]  = g[col];
        btcol[ni] = beta[col];
    }

#pragma unroll
    for (int mi = 0; mi < 4; mi++)
#pragma unroll
    for (int r = 0; r < 4; r++) {
        int lr  = wm * 64 + mi * 16 + rg + r;
        int row = m0 + lr;
        float s = 0.f;
#pragma unroll
        for (int ni = 0; ni < 4; ni++) {
            int col = wn * 64 + ni * 16 + cl;
            float v = acc[mi][ni][r] + bcol[ni] + xio[(size_t)row * 256 + col];
            acc[mi][ni][r] = v;
            s += v;
        }
        s += __shfl_xor(s, 1); s += __shfl_xor(s, 2);
        s += __shfl_xor(s, 4); s += __shfl_xor(s, 8);
        if (cl == 0) sred1[lr][wn] = s;
    }
    __syncthreads();

    float mu[4][4];
#pragma unroll
    for (int mi = 0; mi < 4; mi++)
#pragma unroll
    for (int r = 0; r < 4; r++) {
        int lr = wm * 64 + mi * 16 + rg + r;
        mu[mi][r] = (sred1[lr][0] + sred1[lr][1] + sred1[lr][2] + sred1[lr][3]) * (1.f / 256.f);
        float s2 = 0.f;
#pragma unroll
        for (int ni = 0; ni < 4; ni++) {
            float d = acc[mi][ni][r] - mu[mi][r];
            s2 += d * d;
        }
        s2 += __shfl_xor(s2, 1); s2 += __shfl_xor(s2, 2);
        s2 += __shfl_xor(s2, 4); s2 += __shfl_xor(s2, 8);
        if (cl == 0) sred2[lr][wn] = s2;
    }
    __syncthreads();

#pragma unroll
    for (int mi = 0; mi < 4; mi++)
#pragma unroll
    for (int r = 0; r < 4; r++) {
        int lr  = wm * 64 + mi * 16 + rg + r;
        int row = m0 + lr;
        float var = (sred2[lr][0] + sred2[lr][1] + sred2[lr][2] + sred2[lr][3]) * (1.f / 256.f);
        float rstd = rsqrtf(var + 1e-5f);
#pragma unroll
        for (int ni = 0; ni < 4; ni++) {
            int col = wn * 64 + ni * 16 + cl;
            size_t idx = (size_t)row * 256 + col;
            float o = (acc[mi][ni][r] - mu[mi][r]) * rstd * gcol[ni] + btcol[ni];
            xio[idx] = o;
            xbf[idx] = __float2bfloat16(o);
            if (WRITE_Q)
                qout[idx] = __float2bfloat16(o + bf2f(__builtin_bit_cast(unsigned short, posb[idx])));
        }
    }
}

// ---------- deformable sampling v4 ----------
__global__ __launch_bounds__(256) void k_sample4(const __hip_bfloat16* __restrict__ val,
                                                 const __half* __restrict__ offh,
                                                 const float* __restrict__ logits,
                                                 __hip_bfloat16* __restrict__ out)
{
    __shared__ int2 sIW[4 * 64 * 17];

    int t  = threadIdx.x;
    int qb = blockIdx.x;

#pragma unroll
    for (int it = 0; it < 4; it++) {
        int item = t + it * 256;
        int qi = item >> 7;
        int pt = item & 127;
        int bs = qb * 8 + qi;
        int b  = bs / LQ_;
        int s  = bs % LQ_;
        int h  = pt >> 4, lv = (pt >> 2) & 3;

        float lg = logits[(size_t)bs * 128 + pt];
        float mx = lg;
#pragma unroll
        for (int m = 1; m < 16; m <<= 1) mx = fmaxf(mx, __shfl_xor(mx, m));
        float ex = __expf(lg - mx);
        float sm = ex;
#pragma unroll
        for (int m = 1; m < 16; m <<= 1) sm += __shfl_xor(sm, m);
        float aw = ex / sm;

        int p0, Wq;
        if (s < 16384)      { p0 = s;         Wq = 128; }
        else if (s < 20480) { p0 = s - 16384; Wq = 64;  }
        else if (s < 21504) { p0 = s - 20480; Wq = 32;  }
        else                { p0 = s - 21504; Wq = 16;  }
        float invWq = 1.f / (float)Wq;
        float refx = ((p0 % Wq) + 0.5f) * invWq;
        float refy = ((p0 / Wq) + 0.5f) * invWq;

        int W  = 128 >> lv;
        int S0 = (65536 - (65536 >> (2 * lv))) / 3;
        float fW = (float)W;

        __half2 o2 = ((const __half2*)(offh + (size_t)bs * 256))[pt];
        float ox = __low2float(o2), oy = __high2float(o2);
        float xx = refx * fW + ox - 0.5f;
        float yy = refy * fW + oy - 0.5f;
        float x0f = floorf(xx), y0f = floorf(yy);
        float wx = xx - x0f, wy = yy - y0f;
        int x0 = (int)x0f, y0 = (int)y0f;
        int x1 = x0 + 1, y1 = y0 + 1;
        bool vx0 = (x0 >= 0) & (x0 < W), vx1 = (x1 >= 0) & (x1 < W);
        bool vy0 = (y0 >= 0) & (y0 < W), vy1 = (y1 >= 0) & (y1 < W);
        int cx0 = min(max(x0, 0), W - 1), cx1 = min(max(x1, 0), W - 1);
        int cy0 = min(max(y0, 0), W - 1), cy1 = min(max(y1, 0), W - 1);

        int rowbase = (b * LQ_ + S0) * C_ + h * DH_;
        int g  = item >> 4;
        int pj = pt & 15;
        int i00 = (rowbase + (cy0 * W + cx0) * C_) * 2;
        int i10 = (rowbase + (cy0 * W + cx1) * C_) * 2;
        int i01 = (rowbase + (cy1 * W + cx0) * C_) * 2;
        int i11 = (rowbase + (cy1 * W + cx1) * C_) * 2;
        float w00 = aw * (1.f - wx) * (1.f - wy) * ((vx0 & vy0) ? 1.f : 0.f);
        float w10 = aw * wx * (1.f - wy) * ((vx1 & vy0) ? 1.f : 0.f);
        float w01 = aw * (1.f - wx) * wy * ((vx0 & vy1) ? 1.f : 0.f);
        float w11 = aw * wx * wy * ((vx1 & vy1) ? 1.f : 0.f);
        sIW[(0 * 64 + g) * 17 + pj] = make_int2(i00, __float_as_int(w00));
        sIW[(1 * 64 + g) * 17 + pj] = make_int2(i10, __float_as_int(w10));
        sIW[(2 * 64 + g) * 17 + pj] = make_int2(i01, __float_as_int(w01));
        sIW[(3 * 64 + g) * 17 + pj] = make_int2(i11, __float_as_int(w11));
    }
    __syncthreads();

    {
        int g  = t >> 2;
        int dq = t & 3;
        int bs = qb * 8 + (g >> 3);
        int h  = g & 7;
        int dbyte = dq * 16;

        const char* vbase = (const char*)val;
        float a0 = 0.f, a1 = 0.f, a2 = 0.f, a3 = 0.f;
        float a4 = 0.f, a5 = 0.f, a6 = 0.f, a7 = 0.f;
#pragma unroll
        for (int j = 0; j < 16; j++) {
#pragma unroll
            for (int k = 0; k < 4; k++) {
                int2 iw = sIW[(k * 64 + g) * 17 + j];
                float w = __int_as_float(iw.y);
                uint4 u = *(const uint4*)(vbase + iw.x + dbyte);
                a0 = fmaf(w, __builtin_bit_cast(float, u.x << 16), a0);
                a1 = fmaf(w, __builtin_bit_cast(float, u.x & 0xffff0000u), a1);
                a2 = fmaf(w, __builtin_bit_cast(float, u.y << 16), a2);
                a3 = fmaf(w, __builtin_bit_cast(float, u.y & 0xffff0000u), a3);
                a4 = fmaf(w, __builtin_bit_cast(float, u.z << 16), a4);
                a5 = fmaf(w, __builtin_bit_cast(float, u.z & 0xffff0000u), a5);
                a6 = fmaf(w, __builtin_bit_cast(float, u.w << 16), a6);
                a7 = fmaf(w, __builtin_bit_cast(float, u.w & 0xffff0000u), a7);
            }
        }
        uint4 o;
        o.x = (unsigned)f2bf(a0) | ((unsigned)f2bf(a1) << 16);
        o.y = (unsigned)f2bf(a2) | ((unsigned)f2bf(a3) << 16);
        o.z = (unsigned)f2bf(a4) | ((unsigned)f2bf(a5) << 16);
        o.w = (unsigned)f2bf(a6) | ((unsigned)f2bf(a7) << 16);
        *(uint4*)((char*)out + (size_t)bs * 512 + h * 64 + dbyte) = o;
    }
}

// ---------- driver ----------
extern "C" void kernel_launch(void* const* d_in, const int* in_sizes, int n_in,
                              void* d_out, int out_size, void* d_ws, size_t ws_size,
                              hipStream_t stream)
{
    const float* src_[4] = {(const float*)d_in[0], (const float*)d_in[2],
                            (const float*)d_in[4], (const float*)d_in[6]};
    const float* pos_[4] = {(const float*)d_in[1], (const float*)d_in[3],
                            (const float*)d_in[5], (const float*)d_in[7]};
    const float* lev   = (const float*)d_in[8];
    const float* Woff  = (const float*)d_in[9];
    const float* boff  = (const float*)d_in[10];
    const float* Wattn = (const float*)d_in[11];
    const float* battn = (const float*)d_in[12];
    const float* Wval  = (const float*)d_in[13];
    const float* bval  = (const float*)d_in[14];
    const float* Wout  = (const float*)d_in[15];
    const float* bout  = (const float*)d_in[16];
    const float* g1    = (const float*)d_in[17];
    const float* b1    = (const float*)d_in[18];
    const float* Wff1  = (const float*)d_in[19];
    const float* bff1  = (const float*)d_in[20];
    const float* Wff2  = (const float*)d_in[21];
    const float* bff2  = (const float*)d_in[22];
    const float* g2    = (const float*)d_in[23];
    const float* b2    = (const float*)d_in[24];

    float* x = (float*)d_out;                       // persistent hidden state (fp32)
    size_t MC = (size_t)M_ * C_;                    // 11,141,120

    // layout (each mid segment = M*512 bytes):
    // pos | q | x_bf | offh(f16 M*256) | attb(f32 M*128) | val_bf | pad | weights
    // ffh [M,1024] bf16 aliases offh..pad exactly (4 x M*512 B).
    __hip_bfloat16* pos_bf = (__hip_bfloat16*)d_ws;
    __hip_bfloat16* q_bf   = pos_bf + MC;
    __hip_bfloat16* x_bf   = q_bf + MC;
    __half* offh           = (__half*)(x_bf + MC);            // M*256 f16
    float*  attb           = (float*)(offh + MC);             // M*128 f32
    __hip_bfloat16* val_bf = (__hip_bfloat16*)(attb + (size_t)M_ * 128);
    __hip_bfloat16* pad_bf = val_bf + MC;                     // ffh tail
    __hip_bfloat16* ffh_bf = (__hip_bfloat16*)offh;           // [M,1024] alias
    __hip_bfloat16* wbf    = pad_bf + MC;

    __hip_bfloat16* wq    = wbf;                        // 6*384*256
    __hip_bfloat16* wvalt = wq    + 6 * 98304;
    __hip_bfloat16* woutf = wvalt + 6 * 65536;          // frag layout
    __hip_bfloat16* wff1t = woutf + 6 * 65536;
    __hip_bfloat16* wff2f = wff1t + 6 * 262144;         // frag layout

    dim3 blk(256);
    dim3 tblk(32, 8);

    k_wt<<<dim3(8, 8, 6),  tblk, 0, stream>>>(Woff,  wq,             256, 256,  98304);
    k_wt<<<dim3(4, 8, 6),  tblk, 0, stream>>>(Wattn, wq + 256 * 256, 256, 128,  98304);
    k_wt<<<dim3(8, 8, 6),  tblk, 0, stream>>>(Wval,  wvalt,          256, 256,  65536);
    k_wt<<<dim3(32, 8, 6), tblk, 0, stream>>>(Wff1,  wff1t,          256, 1024, 262144);
    k_wt2<<<dim3(4, 8, 6),  blk, 0, stream>>>(Wout,  woutf,          256, 256,  65536);
    k_wt2<<<dim3(4, 32, 6), blk, 0, stream>>>(Wff2,  wff2f,          1024, 256, 262144);

    k_assemble2<<<10880, blk, 0, stream>>>(
        src_[0], src_[1], src_[2], src_[3],
        pos_[0], pos_[1], pos_[2], pos_[3], lev, x, x_bf, pos_bf, q_bf);

    for (int l = 0; l < 6; l++) {
        // off (f16) + attn logits (f32) in one GEMM (N=384)
        k_gemm_qa<<<dim3(M_ / 128, 3), blk, 0, stream>>>(
            q_bf, wq + (size_t)l * 98304, boff + l * 256, battn + l * 128,
            offh, attb, M_);

        // val = x @ Wval + bval  [M,256] bf16  (staged 128x128)
        k_gemm_mfma<false, true><<<dim3(M_ / 128, 2), blk, 0, stream>>>(
            x_bf, wvalt + (size_t)l * 65536, bval + l * 256, val_bf, M_, 256, C_);

        // deformable sampling (softmax fused) -> q_bf
        k_sample4<<<M_ / 8, blk, 0, stream>>>(val_bf, offh, attb, q_bf);

        // out-proj + bias + residual + LN -> x, x_bf  (A-dbuf, frag-B)
        k_gemm_lnf<false><<<M_ / 128, 512, 0, stream>>>(
            q_bf, woutf + (size_t)l * 65536, bout + l * 256,
            x, x_bf, g1 + l * 256, b1 + l * 256, nullptr, nullptr, M_, 256);

        // FF1: ffh = relu(x@W1+b1)  (staged 128x128 tiles)
        k_gemm_mfma<true, true><<<dim3(M_ / 128, 8), blk, 0, stream>>>(
            x_bf, wff1t + (size_t)l * 262144, bff1 + l * DFF_, ffh_bf, M_, DFF_, C_);

        // FF2 + residual + LN (+ q for next layer)  (A-dbuf, frag-B)
        if (l < 5)
            k_gemm_lnf<true><<<M_ / 128, 512, 0, stream>>>(
                ffh_bf, wff2f + (size_t)l * 262144, bff2 + l * C_,
                x, x_bf, g2 + l * 256, b2 + l * 256, pos_bf, q_bf, M_, DFF_);
        else
            k_gemm_lnf<false><<<M_ / 128, 512, 0, stream>>>(
                ffh_bf, wff2f + (size_t)l * 262144, bff2 + l * C_,
                x, x_bf, g2 + l * 256, b2 + l * 256, nullptr, nullptr, M_, DFF_);
    }
}

// Round 13
// 1754.251 us; speedup vs baseline: 1.2474x; 1.0693x over previous
//
#include <hip/hip_runtime.h>
#include <hip/hip_bf16.h>
#include <hip/hip_fp16.h>
#include <math.h>

namespace {
constexpr int B_   = 2;
constexpr int C_   = 256;
constexpr int NH_  = 8;
constexpr int DH_  = 32;
constexpr int NP_  = 4;
constexpr int DFF_ = 1024;
constexpr int LQ_  = 21760;
constexpr int M_   = B_ * LQ_;     // 43520
}

typedef __bf16  bf16x8 __attribute__((ext_vector_type(8)));
typedef short   s16x8  __attribute__((ext_vector_type(8)));
typedef float   f32x4  __attribute__((ext_vector_type(4)));

#define AS1 __attribute__((address_space(1)))
#define AS3 __attribute__((address_space(3)))

static __device__ __forceinline__ unsigned short f2bf(float f) {
    return __builtin_bit_cast(unsigned short, __float2bfloat16(f));
}
static __device__ __forceinline__ float bf2f(unsigned short u) {
    return __bfloat162float(__builtin_bit_cast(__hip_bfloat16, u));
}

// ---------- weight transpose + cvt: in [L][K][N] f32 -> out rows [N][K] bf16 ----------
__global__ void k_wt(const float* __restrict__ in, __hip_bfloat16* __restrict__ out,
                     int K, int N, int outStride)
{
    __shared__ float tile[32][33];
    int n0 = blockIdx.x * 32, k0 = blockIdx.y * 32;
    const float* inl = in + (size_t)blockIdx.z * K * N;
    __hip_bfloat16* outl = out + (size_t)blockIdx.z * outStride;
    for (int i = threadIdx.y; i < 32; i += 8)
        tile[i][threadIdx.x] = inl[(size_t)(k0 + i) * N + n0 + threadIdx.x];
    __syncthreads();
    for (int i = threadIdx.y; i < 32; i += 8)
        outl[(size_t)(n0 + i) * K + k0 + threadIdx.x] = __float2bfloat16(tile[threadIdx.x][i]);
}

// ---------- coalesced assemble via LDS transpose ----------
__global__ __launch_bounds__(256) void k_assemble2(
    const float* __restrict__ s0, const float* __restrict__ s1,
    const float* __restrict__ s2, const float* __restrict__ s3,
    const float* __restrict__ p0, const float* __restrict__ p1,
    const float* __restrict__ p2, const float* __restrict__ p3,
    const float* __restrict__ lev, float* __restrict__ x,
    __hip_bfloat16* __restrict__ xbf, __hip_bfloat16* __restrict__ posbf,
    __hip_bfloat16* __restrict__ qbf)
{
    int bid = blockIdx.x;
    int lv, rem, HW, S0;
    const float *sp, *pp;
    if (bid < 8192)       { lv = 0; rem = bid;         HW = 16384; S0 = 0;     sp = s0; pp = p0; }
    else if (bid < 10240) { lv = 1; rem = bid - 8192;  HW = 4096;  S0 = 16384; sp = s1; pp = p1; }
    else if (bid < 10752) { lv = 2; rem = bid - 10240; HW = 1024;  S0 = 20480; sp = s2; pp = p2; }
    else                  { lv = 3; rem = bid - 10752; HW = 256;   S0 = 21504; sp = s3; pp = p3; }
    int sptiles = HW >> 5;
    int spt = rem % sptiles;
    int ct  = (rem / sptiles) & 7;
    int b   = rem / (sptiles * 8);
    int sp0 = spt * 32, c0 = ct * 32;

    __shared__ float ts[32][33], tp[32][33];
    int tx = threadIdx.x & 31, ty = threadIdx.x >> 5;
#pragma unroll
    for (int i = 0; i < 4; i++) {
        int c = c0 + ty + i * 8;
        size_t si = ((size_t)(b * C_ + c)) * HW + sp0 + tx;
        ts[ty + i * 8][tx] = sp[si];
        tp[ty + i * 8][tx] = pp[si];
    }
    __syncthreads();
#pragma unroll
    for (int i = 0; i < 4; i++) {
        int s = S0 + sp0 + ty + i * 8;
        int c = c0 + tx;
        float sv = ts[tx][ty + i * 8];
        float pv = tp[tx][ty + i * 8] + lev[lv * C_ + c];
        size_t idx = ((size_t)(b * LQ_ + s)) * C_ + c;
        x[idx]     = sv;
        xbf[idx]   = __float2bfloat16(sv);
        posbf[idx] = __float2bfloat16(pv);
        qbf[idx]   = __float2bfloat16(sv + pv);
    }
}

// ---------- bf16 MFMA GEMM (staged 128x128): out = A[M,K] @ W^T + bias ----------
template<bool RELU, bool BF16OUT>
__global__ __launch_bounds__(256) void k_gemm_mfma(
    const __hip_bfloat16* __restrict__ A,
    const __hip_bfloat16* __restrict__ Wt,
    const float* __restrict__ bias,
    void* __restrict__ Co,
    int M, int N, int K)
{
    __shared__ char As[128 * 128];
    __shared__ char Bs[128 * 128];
    int t = threadIdx.x, w = t >> 6, lane = t & 63;
    int m0 = blockIdx.x * 128, n0 = blockIdx.y * 128;
    int wm = w >> 1, wn = w & 1;

    f32x4 acc[4][4] = {};

    int rowoff  = lane >> 3;
    int colswz  = ((lane & 7) ^ (lane >> 3)) << 3;

    for (int kt = 0; kt < K; kt += 64) {
#pragma unroll
        for (int j = 0; j < 4; j++) {
            int rowbase = w * 32 + j * 8;
            const __hip_bfloat16* srcA = A  + (size_t)(m0 + rowbase + rowoff) * K + kt + colswz;
            const __hip_bfloat16* srcB = Wt + (size_t)(n0 + rowbase + rowoff) * K + kt + colswz;
            __builtin_amdgcn_global_load_lds(
                (const AS1 void*)srcA, (AS3 void*)(As + rowbase * 128), 16, 0, 0);
            __builtin_amdgcn_global_load_lds(
                (const AS1 void*)srcB, (AS3 void*)(Bs + rowbase * 128), 16, 0, 0);
        }
        __syncthreads();
#pragma unroll
        for (int k0 = 0; k0 < 64; k0 += 32) {
            int kb = k0 * 2 + (lane >> 4) * 16;
            bf16x8 af[4], bfr[4];
#pragma unroll
            for (int mi = 0; mi < 4; mi++) {
                int r = wm * 64 + mi * 16 + (lane & 15);
                s16x8 raw = *(const s16x8*)(As + r * 128 + (kb ^ ((r & 7) << 4)));
                af[mi] = __builtin_bit_cast(bf16x8, raw);
            }
#pragma unroll
            for (int ni = 0; ni < 4; ni++) {
                int r = wn * 64 + ni * 16 + (lane & 15);
                s16x8 raw = *(const s16x8*)(Bs + r * 128 + (kb ^ ((r & 7) << 4)));
                bfr[ni] = __builtin_bit_cast(bf16x8, raw);
            }
#pragma unroll
            for (int mi = 0; mi < 4; mi++)
#pragma unroll
                for (int ni = 0; ni < 4; ni++)
                    acc[mi][ni] = __builtin_amdgcn_mfma_f32_16x16x32_bf16(
                        af[mi], bfr[ni], acc[mi][ni], 0, 0, 0);
        }
        __syncthreads();
    }

#pragma unroll
    for (int ni = 0; ni < 4; ni++) {
        int col = n0 + wn * 64 + ni * 16 + (lane & 15);
        float bb = bias[col];
#pragma unroll
        for (int mi = 0; mi < 4; mi++) {
            int row = m0 + wm * 64 + mi * 16 + ((lane >> 4) << 2);
#pragma unroll
            for (int r = 0; r < 4; r++) {
                float v = acc[mi][ni][r] + bb;
                if (RELU) v = fmaxf(v, 0.f);
                if (BF16OUT)
                    ((__hip_bfloat16*)Co)[(size_t)(row + r) * N + col] = __float2bfloat16(v);
                else
                    ((float*)Co)[(size_t)(row + r) * N + col] = v;
            }
        }
    }
}

// ---------- merged q/attn/val GEMM, grid (M/128, 5) ----------
// y=0,1: offh = q @ Woff (f16)   y=2: attb = q @ Wattn (f32)
// y=3,4: val  = x @ Wval (bf16)
__global__ __launch_bounds__(256) void k_gemm_qav(
    const __hip_bfloat16* __restrict__ Aq,    // [M,256] q
    const __hip_bfloat16* __restrict__ Ax,    // [M,256] x
    const __hip_bfloat16* __restrict__ Wqv,   // [640,256]: off 0-255, attn 256-383, val 384-639
    const float* __restrict__ boff, const float* __restrict__ battn,
    const float* __restrict__ bval,
    __half* __restrict__ offh, float* __restrict__ attb,
    __hip_bfloat16* __restrict__ valb, int M)
{
    constexpr int K = 256;
    __shared__ char As[128 * 128];
    __shared__ char Bs[128 * 128];
    int t = threadIdx.x, w = t >> 6, lane = t & 63;
    int by = blockIdx.y;
    int m0 = blockIdx.x * 128, n0 = by * 128;
    int wm = w >> 1, wn = w & 1;
    const __hip_bfloat16* A = (by < 3) ? Aq : Ax;

    f32x4 acc[4][4] = {};
    int rowoff  = lane >> 3;
    int colswz  = ((lane & 7) ^ (lane >> 3)) << 3;

    for (int kt = 0; kt < K; kt += 64) {
#pragma unroll
        for (int j = 0; j < 4; j++) {
            int rowbase = w * 32 + j * 8;
            const __hip_bfloat16* srcA = A   + (size_t)(m0 + rowbase + rowoff) * K + kt + colswz;
            const __hip_bfloat16* srcB = Wqv + (size_t)(n0 + rowbase + rowoff) * K + kt + colswz;
            __builtin_amdgcn_global_load_lds(
                (const AS1 void*)srcA, (AS3 void*)(As + rowbase * 128), 16, 0, 0);
            __builtin_amdgcn_global_load_lds(
                (const AS1 void*)srcB, (AS3 void*)(Bs + rowbase * 128), 16, 0, 0);
        }
        __syncthreads();
#pragma unroll
        for (int k0 = 0; k0 < 64; k0 += 32) {
            int kb = k0 * 2 + (lane >> 4) * 16;
            bf16x8 af[4], bfr[4];
#pragma unroll
            for (int mi = 0; mi < 4; mi++) {
                int r = wm * 64 + mi * 16 + (lane & 15);
                s16x8 raw = *(const s16x8*)(As + r * 128 + (kb ^ ((r & 7) << 4)));
                af[mi] = __builtin_bit_cast(bf16x8, raw);
            }
#pragma unroll
            for (int ni = 0; ni < 4; ni++) {
                int r = wn * 64 + ni * 16 + (lane & 15);
                s16x8 raw = *(const s16x8*)(Bs + r * 128 + (kb ^ ((r & 7) << 4)));
                bfr[ni] = __builtin_bit_cast(bf16x8, raw);
            }
#pragma unroll
            for (int mi = 0; mi < 4; mi++)
#pragma unroll
                for (int ni = 0; ni < 4; ni++)
                    acc[mi][ni] = __builtin_amdgcn_mfma_f32_16x16x32_bf16(
                        af[mi], bfr[ni], acc[mi][ni], 0, 0, 0);
        }
        __syncthreads();
    }

    if (by == 2) {               // attn logits f32 [M,128]
#pragma unroll
        for (int ni = 0; ni < 4; ni++) {
            int col = wn * 64 + ni * 16 + (lane & 15);
            float bb = battn[col];
#pragma unroll
            for (int mi = 0; mi < 4; mi++) {
                int row = m0 + wm * 64 + mi * 16 + ((lane >> 4) << 2);
#pragma unroll
                for (int r = 0; r < 4; r++)
                    attb[(size_t)(row + r) * 128 + col] = acc[mi][ni][r] + bb;
            }
        }
    } else if (by < 2) {         // off f16 [M,256]
#pragma unroll
        for (int ni = 0; ni < 4; ni++) {
            int col = n0 + wn * 64 + ni * 16 + (lane & 15);
            float bb = boff[col];
#pragma unroll
            for (int mi = 0; mi < 4; mi++) {
                int row = m0 + wm * 64 + mi * 16 + ((lane >> 4) << 2);
#pragma unroll
                for (int r = 0; r < 4; r++)
                    offh[(size_t)(row + r) * 256 + col] = __float2half(acc[mi][ni][r] + bb);
            }
        }
    } else {                     // val bf16 [M,256]
        int nb = n0 - 384;
#pragma unroll
        for (int ni = 0; ni < 4; ni++) {
            int col = nb + wn * 64 + ni * 16 + (lane & 15);
            float bb = bval[col];
#pragma unroll
            for (int mi = 0; mi < 4; mi++) {
                int row = m0 + wm * 64 + mi * 16 + ((lane >> 4) << 2);
#pragma unroll
                for (int r = 0; r < 4; r++)
                    valb[(size_t)(row + r) * 256 + col] =
                        __float2bfloat16(acc[mi][ni][r] + bb);
            }
        }
    }
}

// ---------- GEMM (N=256) + bias + residual + LN, BM=128, full A+B dbuf ----------
template<bool WRITE_Q>
__global__ __launch_bounds__(512) void k_gemm_ln(
    const __hip_bfloat16* __restrict__ A,    // [M,K]
    const __hip_bfloat16* __restrict__ Wt,   // [256,K]
    const float* __restrict__ bias,
    float* __restrict__ xio,
    __hip_bfloat16* __restrict__ xbf,
    const float* __restrict__ g, const float* __restrict__ beta,
    const __hip_bfloat16* __restrict__ posb,
    __hip_bfloat16* __restrict__ qout,
    int M, int K)
{
    __shared__ char As[2][128 * 128];
    __shared__ char Bs[2][256 * 128];
    __shared__ float sred1[128][4];
    __shared__ float sred2[128][4];

    int t = threadIdx.x, w = t >> 6, lane = t & 63;
    int m0 = blockIdx.x * 128;
    int wm = w >> 2, wn = w & 3;

    f32x4 acc[4][4] = {};

    int rowoff  = lane >> 3;
    int colswz  = ((lane & 7) ^ rowoff) << 3;

    auto STAGE = [&](char* Ab, char* Bb, int kt) {
#pragma unroll
        for (int j = 0; j < 2; j++) {
            int rowbase = w * 16 + j * 8;
            const __hip_bfloat16* srcA = A + (size_t)(m0 + rowbase + rowoff) * K + kt + colswz;
            __builtin_amdgcn_global_load_lds(
                (const AS1 void*)srcA, (AS3 void*)(Ab + rowbase * 128), 16, 0, 0);
        }
#pragma unroll
        for (int j = 0; j < 4; j++) {
            int rowbase = w * 32 + j * 8;
            const __hip_bfloat16* srcB = Wt + (size_t)(rowbase + rowoff) * K + kt + colswz;
            __builtin_amdgcn_global_load_lds(
                (const AS1 void*)srcB, (AS3 void*)(Bb + rowbase * 128), 16, 0, 0);
        }
    };

    STAGE(As[0], Bs[0], 0);
    asm volatile("s_waitcnt vmcnt(0)" ::: "memory");
    __builtin_amdgcn_s_barrier();

    const int nt = K >> 6;
    int cur = 0;
    for (int tt = 0; tt < nt; ++tt) {
        if (tt + 1 < nt) STAGE(As[cur ^ 1], Bs[cur ^ 1], (tt + 1) << 6);
        const char* Ab = As[cur];
        const char* Bb = Bs[cur];
#pragma unroll
        for (int k0 = 0; k0 < 64; k0 += 32) {
            int kb = k0 * 2 + (lane >> 4) * 16;
            bf16x8 af[4], bfr[4];
#pragma unroll
            for (int mi = 0; mi < 4; mi++) {
                int r = wm * 64 + mi * 16 + (lane & 15);
                s16x8 raw = *(const s16x8*)(Ab + r * 128 + (kb ^ ((r & 7) << 4)));
                af[mi] = __builtin_bit_cast(bf16x8, raw);
            }
#pragma unroll
            for (int ni = 0; ni < 4; ni++) {
                int r = wn * 64 + ni * 16 + (lane & 15);
                s16x8 raw = *(const s16x8*)(Bb + r * 128 + (kb ^ ((r & 7) << 4)));
                bfr[ni] = __builtin_bit_cast(bf16x8, raw);
            }
#pragma unroll
            for (int mi = 0; mi < 4; mi++)
#pragma unroll
                for (int ni = 0; ni < 4; ni++)
                    acc[mi][ni] = __builtin_amdgcn_mfma_f32_16x16x32_bf16(
                        af[mi], bfr[ni], acc[mi][ni], 0, 0, 0);
        }
        asm volatile("s_waitcnt vmcnt(0)" ::: "memory");
        __builtin_amdgcn_s_barrier();
        cur ^= 1;
    }

    // ---- fused bias + residual + LN epilogue ----
    int cl = lane & 15;
    int rg = (lane >> 4) << 2;
    float bcol[4], gcol[4], btcol[4];
#pragma unroll
    for (int ni = 0; ni < 4; ni++) {
        int col = wn * 64 + ni * 16 + cl;
        bcol[ni]  = bias[col];
        gcol[ni]  = g[col];
        btcol[ni] = beta[col];
    }

#pragma unroll
    for (int mi = 0; mi < 4; mi++)
#pragma unroll
    for (int r = 0; r < 4; r++) {
        int lr  = wm * 64 + mi * 16 + rg + r;
        int row = m0 + lr;
        float s = 0.f;
#pragma unroll
        for (int ni = 0; ni < 4; ni++) {
            int col = wn * 64 + ni * 16 + cl;
            float v = acc[mi][ni][r] + bcol[ni] + xio[(size_t)row * 256 + col];
            acc[mi][ni][r] = v;
            s += v;
        }
        s += __shfl_xor(s, 1); s += __shfl_xor(s, 2);
        s += __shfl_xor(s, 4); s += __shfl_xor(s, 8);
        if (cl == 0) sred1[lr][wn] = s;
    }
    __syncthreads();

    float mu[4][4];
#pragma unroll
    for (int mi = 0; mi < 4; mi++)
#pragma unroll
    for (int r = 0; r < 4; r++) {
        int lr = wm * 64 + mi * 16 + rg + r;
        mu[mi][r] = (sred1[lr][0] + sred1[lr][1] + sred1[lr][2] + sred1[lr][3]) * (1.f / 256.f);
        float s2 = 0.f;
#pragma unroll
        for (int ni = 0; ni < 4; ni++) {
            float d = acc[mi][ni][r] - mu[mi][r];
            s2 += d * d;
        }
        s2 += __shfl_xor(s2, 1); s2 += __shfl_xor(s2, 2);
        s2 += __shfl_xor(s2, 4); s2 += __shfl_xor(s2, 8);
        if (cl == 0) sred2[lr][wn] = s2;
    }
    __syncthreads();

#pragma unroll
    for (int mi = 0; mi < 4; mi++)
#pragma unroll
    for (int r = 0; r < 4; r++) {
        int lr  = wm * 64 + mi * 16 + rg + r;
        int row = m0 + lr;
        float var = (sred2[lr][0] + sred2[lr][1] + sred2[lr][2] + sred2[lr][3]) * (1.f / 256.f);
        float rstd = rsqrtf(var + 1e-5f);
#pragma unroll
        for (int ni = 0; ni < 4; ni++) {
            int col = wn * 64 + ni * 16 + cl;
            size_t idx = (size_t)row * 256 + col;
            float o = (acc[mi][ni][r] - mu[mi][r]) * rstd * gcol[ni] + btcol[ni];
            xio[idx] = o;
            xbf[idx] = __float2bfloat16(o);
            if (WRITE_Q)
                qout[idx] = __float2bfloat16(o + bf2f(__builtin_bit_cast(unsigned short, posb[idx])));
        }
    }
}

// ---------- deformable sampling v4 ----------
__global__ __launch_bounds__(256) void k_sample4(const __hip_bfloat16* __restrict__ val,
                                                 const __half* __restrict__ offh,
                                                 const float* __restrict__ logits,
                                                 __hip_bfloat16* __restrict__ out)
{
    __shared__ int2 sIW[4 * 64 * 17];

    int t  = threadIdx.x;
    int qb = blockIdx.x;

#pragma unroll
    for (int it = 0; it < 4; it++) {
        int item = t + it * 256;
        int qi = item >> 7;
        int pt = item & 127;
        int bs = qb * 8 + qi;
        int b  = bs / LQ_;
        int s  = bs % LQ_;
        int h  = pt >> 4, lv = (pt >> 2) & 3;

        float lg = logits[(size_t)bs * 128 + pt];
        float mx = lg;
#pragma unroll
        for (int m = 1; m < 16; m <<= 1) mx = fmaxf(mx, __shfl_xor(mx, m));
        float ex = __expf(lg - mx);
        float sm = ex;
#pragma unroll
        for (int m = 1; m < 16; m <<= 1) sm += __shfl_xor(sm, m);
        float aw = ex / sm;

        int p0, Wq;
        if (s < 16384)      { p0 = s;         Wq = 128; }
        else if (s < 20480) { p0 = s - 16384; Wq = 64;  }
        else if (s < 21504) { p0 = s - 20480; Wq = 32;  }
        else                { p0 = s - 21504; Wq = 16;  }
        float invWq = 1.f / (float)Wq;
        float refx = ((p0 % Wq) + 0.5f) * invWq;
        float refy = ((p0 / Wq) + 0.5f) * invWq;

        int W  = 128 >> lv;
        int S0 = (65536 - (65536 >> (2 * lv))) / 3;
        float fW = (float)W;

        __half2 o2 = ((const __half2*)(offh + (size_t)bs * 256))[pt];
        float ox = __low2float(o2), oy = __high2float(o2);
        float xx = refx * fW + ox - 0.5f;
        float yy = refy * fW + oy - 0.5f;
        float x0f = floorf(xx), y0f = floorf(yy);
        float wx = xx - x0f, wy = yy - y0f;
        int x0 = (int)x0f, y0 = (int)y0f;
        int x1 = x0 + 1, y1 = y0 + 1;
        bool vx0 = (x0 >= 0) & (x0 < W), vx1 = (x1 >= 0) & (x1 < W);
        bool vy0 = (y0 >= 0) & (y0 < W), vy1 = (y1 >= 0) & (y1 < W);
        int cx0 = min(max(x0, 0), W - 1), cx1 = min(max(x1, 0), W - 1);
        int cy0 = min(max(y0, 0), W - 1), cy1 = min(max(y1, 0), W - 1);

        int rowbase = (b * LQ_ + S0) * C_ + h * DH_;
        int g  = item >> 4;
        int pj = pt & 15;
        int i00 = (rowbase + (cy0 * W + cx0) * C_) * 2;
        int i10 = (rowbase + (cy0 * W + cx1) * C_) * 2;
        int i01 = (rowbase + (cy1 * W + cx0) * C_) * 2;
        int i11 = (rowbase + (cy1 * W + cx1) * C_) * 2;
        float w00 = aw * (1.f - wx) * (1.f - wy) * ((vx0 & vy0) ? 1.f : 0.f);
        float w10 = aw * wx * (1.f - wy) * ((vx1 & vy0) ? 1.f : 0.f);
        float w01 = aw * (1.f - wx) * wy * ((vx0 & vy1) ? 1.f : 0.f);
        float w11 = aw * wx * wy * ((vx1 & vy1) ? 1.f : 0.f);
        sIW[(0 * 64 + g) * 17 + pj] = make_int2(i00, __float_as_int(w00));
        sIW[(1 * 64 + g) * 17 + pj] = make_int2(i10, __float_as_int(w10));
        sIW[(2 * 64 + g) * 17 + pj] = make_int2(i01, __float_as_int(w01));
        sIW[(3 * 64 + g) * 17 + pj] = make_int2(i11, __float_as_int(w11));
    }
    __syncthreads();

    {
        int g  = t >> 2;
        int dq = t & 3;
        int bs = qb * 8 + (g >> 3);
        int h  = g & 7;
        int dbyte = dq * 16;

        const char* vbase = (const char*)val;
        float a0 = 0.f, a1 = 0.f, a2 = 0.f, a3 = 0.f;
        float a4 = 0.f, a5 = 0.f, a6 = 0.f, a7 = 0.f;
#pragma unroll
        for (int j = 0; j < 16; j++) {
#pragma unroll
            for (int k = 0; k < 4; k++) {
                int2 iw = sIW[(k * 64 + g) * 17 + j];
                float w = __int_as_float(iw.y);
                uint4 u = *(const uint4*)(vbase + iw.x + dbyte);
                a0 = fmaf(w, __builtin_bit_cast(float, u.x << 16), a0);
                a1 = fmaf(w, __builtin_bit_cast(float, u.x & 0xffff0000u), a1);
                a2 = fmaf(w, __builtin_bit_cast(float, u.y << 16), a2);
                a3 = fmaf(w, __builtin_bit_cast(float, u.y & 0xffff0000u), a3);
                a4 = fmaf(w, __builtin_bit_cast(float, u.z << 16), a4);
                a5 = fmaf(w, __builtin_bit_cast(float, u.z & 0xffff0000u), a5);
                a6 = fmaf(w, __builtin_bit_cast(float, u.w << 16), a6);
                a7 = fmaf(w, __builtin_bit_cast(float, u.w & 0xffff0000u), a7);
            }
        }
        uint4 o;
        o.x = (unsigned)f2bf(a0) | ((unsigned)f2bf(a1) << 16);
        o.y = (unsigned)f2bf(a2) | ((unsigned)f2bf(a3) << 16);
        o.z = (unsigned)f2bf(a4) | ((unsigned)f2bf(a5) << 16);
        o.w = (unsigned)f2bf(a6) | ((unsigned)f2bf(a7) << 16);
        *(uint4*)((char*)out + (size_t)bs * 512 + h * 64 + dbyte) = o;
    }
}

// ---------- driver ----------
extern "C" void kernel_launch(void* const* d_in, const int* in_sizes, int n_in,
                              void* d_out, int out_size, void* d_ws, size_t ws_size,
                              hipStream_t stream)
{
    const float* src_[4] = {(const float*)d_in[0], (const float*)d_in[2],
                            (const float*)d_in[4], (const float*)d_in[6]};
    const float* pos_[4] = {(const float*)d_in[1], (const float*)d_in[3],
                            (const float*)d_in[5], (const float*)d_in[7]};
    const float* lev   = (const float*)d_in[8];
    const float* Woff  = (const float*)d_in[9];
    const float* boff  = (const float*)d_in[10];
    const float* Wattn = (const float*)d_in[11];
    const float* battn = (const float*)d_in[12];
    const float* Wval  = (const float*)d_in[13];
    const float* bval  = (const float*)d_in[14];
    const float* Wout  = (const float*)d_in[15];
    const float* bout  = (const float*)d_in[16];
    const float* g1    = (const float*)d_in[17];
    const float* b1    = (const float*)d_in[18];
    const float* Wff1  = (const float*)d_in[19];
    const float* bff1  = (const float*)d_in[20];
    const float* Wff2  = (const float*)d_in[21];
    const float* bff2  = (const float*)d_in[22];
    const float* g2    = (const float*)d_in[23];
    const float* b2    = (const float*)d_in[24];

    float* x = (float*)d_out;                       // persistent hidden state (fp32)
    size_t MC = (size_t)M_ * C_;                    // 11,141,120

    // layout (each mid segment = M*512 bytes):
    // pos | q | x_bf | offh(f16 M*256) | attb(f32 M*128) | val_bf | pad | weights
    // ffh [M,1024] bf16 aliases offh..pad exactly (4 x M*512 B).
    __hip_bfloat16* pos_bf = (__hip_bfloat16*)d_ws;
    __hip_bfloat16* q_bf   = pos_bf + MC;
    __hip_bfloat16* x_bf   = q_bf + MC;
    __half* offh           = (__half*)(x_bf + MC);            // M*256 f16
    float*  attb           = (float*)(offh + MC);             // M*128 f32
    __hip_bfloat16* val_bf = (__hip_bfloat16*)(attb + (size_t)M_ * 128);
    __hip_bfloat16* pad_bf = val_bf + MC;                     // ffh tail
    __hip_bfloat16* ffh_bf = (__hip_bfloat16*)offh;           // [M,1024] alias
    __hip_bfloat16* wbf    = pad_bf + MC;

    __hip_bfloat16* wqv   = wbf;                        // 6*640*256 (off|attn|val rows)
    __hip_bfloat16* woutt = wqv   + 6 * 163840;
    __hip_bfloat16* wff1t = woutt + 6 * 65536;
    __hip_bfloat16* wff2t = wff1t + 6 * 262144;

    dim3 blk(256);
    dim3 tblk(32, 8);

    k_wt<<<dim3(8, 8, 6),  tblk, 0, stream>>>(Woff,  wqv,              256, 256,  163840);
    k_wt<<<dim3(4, 8, 6),  tblk, 0, stream>>>(Wattn, wqv + 256 * 256,  256, 128,  163840);
    k_wt<<<dim3(8, 8, 6),  tblk, 0, stream>>>(Wval,  wqv + 384 * 256,  256, 256,  163840);
    k_wt<<<dim3(8, 8, 6),  tblk, 0, stream>>>(Wout,  woutt,            256, 256,  65536);
    k_wt<<<dim3(32, 8, 6), tblk, 0, stream>>>(Wff1,  wff1t,            256, 1024, 262144);
    k_wt<<<dim3(8, 32, 6), tblk, 0, stream>>>(Wff2,  wff2t,            1024, 256, 262144);

    k_assemble2<<<10880, blk, 0, stream>>>(
        src_[0], src_[1], src_[2], src_[3],
        pos_[0], pos_[1], pos_[2], pos_[3], lev, x, x_bf, pos_bf, q_bf);

    for (int l = 0; l < 6; l++) {
        // off (f16) + attn logits (f32) + val (bf16) in ONE dispatch (grid 340x5)
        k_gemm_qav<<<dim3(M_ / 128, 5), blk, 0, stream>>>(
            q_bf, x_bf, wqv + (size_t)l * 163840,
            boff + l * 256, battn + l * 128, bval + l * 256,
            offh, attb, val_bf, M_);

        // deformable sampling (softmax fused) -> q_bf
        k_sample4<<<M_ / 8, blk, 0, stream>>>(val_bf, offh, attb, q_bf);

        // out-proj + bias + residual + LN -> x, x_bf  (full A+B dbuf, K=256)
        k_gemm_ln<false><<<M_ / 128, 512, 0, stream>>>(
            q_bf, woutt + (size_t)l * 65536, bout + l * 256,
            x, x_bf, g1 + l * 256, b1 + l * 256, nullptr, nullptr, M_, 256);

        // FF1: ffh = relu(x@W1+b1)  (staged 128x128 tiles)
        k_gemm_mfma<true, true><<<dim3(M_ / 128, 8), blk, 0, stream>>>(
            x_bf, wff1t + (size_t)l * 262144, bff1 + l * DFF_, ffh_bf, M_, DFF_, C_);

        // FF2 + residual + LN (+ q for next layer)  (full A+B dbuf, K=1024)
        if (l < 5)
            k_gemm_ln<true><<<M_ / 128, 512, 0, stream>>>(
                ffh_bf, wff2t + (size_t)l * 262144, bff2 + l * C_,
                x, x_bf, g2 + l * 256, b2 + l * 256, pos_bf, q_bf, M_, DFF_);
        else
            k_gemm_ln<false><<<M_ / 128, 512, 0, stream>>>(
                ffh_bf, wff2t + (size_t)l * 262144, bff2 + l * C_,
                x, x_bf, g2 + l * 256, b2 + l * 256, nullptr, nullptr, M_, DFF_);
    }
}